// Round 4
// baseline (1907.013 us; speedup 1.0000x reference)
//
#include <hip/hip_runtime.h>
#include <hip/hip_bf16.h>

typedef __hip_bfloat16 bf16;
typedef __attribute__((ext_vector_type(8))) short v8s;
typedef __attribute__((ext_vector_type(4))) float f32x4;
#define EPS 1e-5f
#define MFMA16(a, b, c) __builtin_amdgcn_mfma_f32_16x16x32_bf16(a, b, c, 0, 0, 0)

__device__ __forceinline__ float bfu(unsigned int s) {
  union { unsigned int u; float f; } c; c.u = s << 16; return c.f;
}
__device__ __forceinline__ bf16 f2b(float v) { return __float2bfloat16(v); }

// ---------------------------------------------------------------------------
// K0: tem1 (256x224) and spa1 (64x224) closed-form tables
// ---------------------------------------------------------------------------
__global__ __launch_bounds__(256) void k_small(
    const float* __restrict__ te1_w, const float* __restrict__ te1_b,
    const float* __restrict__ te2_w, const float* __restrict__ te2_b,
    const float* __restrict__ se1_w, const float* __restrict__ se1_b,
    const float* __restrict__ se2_w, const float* __restrict__ se2_b,
    float* __restrict__ tem1, float* __restrict__ spa1) {
  int idx = blockIdx.x * 256 + threadIdx.x;
  if (idx >= (256 + 64) * 224) return;
  int o = idx / 224, t = idx % 224;
  if (o < 256) {
    float acc = te2_b[o];
    for (int c = 0; c < 64; ++c) {
      float u = fmaxf(te1_w[c * 224 + t] + te1_b[c], 0.f);
      acc += te2_w[o * 64 + c] * u;
    }
    tem1[o * 224 + t] = fmaxf(acc, 0.f);
  } else {
    int oo = o - 256;
    float acc = se2_b[oo];
    for (int c = 0; c < 64; ++c) {
      float u = fmaxf(se1_w[c * 224 + t] + se1_b[c], 0.f);
      acc += se2_w[oo * 64 + c] * u;
    }
    spa1[oo * 224 + t] = fmaxf(acc, 0.f);
  }
}

// ---------------------------------------------------------------------------
// K0b: Wm = g1^T g2 fused attention matrix (bf16 hi/lo), dvec = g2^T b1
// ---------------------------------------------------------------------------
__global__ __launch_bounds__(256) void k_wm(
    const float* __restrict__ g1_w, const float* __restrict__ g2_w,
    const float* __restrict__ g1_b, bf16* __restrict__ WmH, bf16* __restrict__ WmL,
    float* __restrict__ dvec) {
  int idx = blockIdx.x * 256 + threadIdx.x;
  if (idx >= 128 * 128) return;
  int o = idx >> 7, c = idx & 127;
  float acc = 0.f;
  for (int t = 0; t < 256; ++t) acc += g1_w[t * 128 + c] * g2_w[t * 128 + o];
  bf16 hi = f2b(acc);
  WmH[o * 128 + c] = hi;
  WmL[o * 128 + c] = f2b(acc - __bfloat162float(hi));
  if (c == 0) {
    float d = 0.f;
    for (int t = 0; t < 256; ++t) d += g2_w[t * 128 + o] * g1_b[t];
    dvec[o] = d;
  }
}

// ---------------------------------------------------------------------------
// K0c: convert the 6 gcn weights to bf16 hi/lo pairs (packed buffer)
// ---------------------------------------------------------------------------
__global__ __launch_bounds__(256) void k_wcvt(
    const float* __restrict__ g1w, const float* __restrict__ g1w1,
    const float* __restrict__ g2w, const float* __restrict__ g2w1,
    const float* __restrict__ g3w, const float* __restrict__ g3w1,
    bf16* __restrict__ dst) {
  int idx = blockIdx.x * 256 + threadIdx.x;
  const float* src; size_t base; int off; int sz;
  if (idx < 16384)        { src = g1w;  base = 0;      off = idx;          sz = 16384; }
  else if (idx < 32768)   { src = g1w1; base = 32768;  off = idx - 16384;  sz = 16384; }
  else if (idx < 65536)   { src = g2w;  base = 65536;  off = idx - 32768;  sz = 32768; }
  else if (idx < 98304)   { src = g2w1; base = 131072; off = idx - 65536;  sz = 32768; }
  else if (idx < 163840)  { src = g3w;  base = 196608; off = idx - 98304;  sz = 65536; }
  else if (idx < 229376)  { src = g3w1; base = 327680; off = idx - 163840; sz = 65536; }
  else return;
  float v = src[off];
  bf16 hi = f2b(v);
  dst[base + off] = hi;
  dst[base + sz + off] = f2b(v - __bfloat162float(hi));
}

// ---------------------------------------------------------------------------
// K1: bn0 + je1 + relu + je2 + relu -> H0[b,t,j,c]
// ---------------------------------------------------------------------------
__global__ __launch_bounds__(256) void k_h0(
    const float* __restrict__ x, const float* __restrict__ bn0,
    const float* __restrict__ je1_w, const float* __restrict__ je1_b,
    const float* __restrict__ je2_w, const float* __restrict__ je2_b,
    const float* __restrict__ spa1, bf16* __restrict__ H0) {
  int bj = blockIdx.x;
  int b = bj / 224, j = bj % 224;
  __shared__ float w1s[192], b1s[64], w2s[4096], b2s[64];
  int tid = threadIdx.x;
  for (int i = tid; i < 192; i += 256) w1s[i] = je1_w[i];
  for (int i = tid; i < 64; i += 256) { b1s[i] = je1_b[i]; b2s[i] = je2_b[i]; }
  for (int i = tid; i < 4096; i += 256) w2s[i] = je2_w[i];
  __syncthreads();
  int t = tid;
  if (t >= 224) return;
  float xf[3];
  #pragma unroll
  for (int c = 0; c < 3; ++c) {
    int ch = c * 224 + j;
    float g = bn0[ch], bb = bn0[672 + ch], m = bn0[2 * 672 + ch], v = bn0[3 * 672 + ch];
    float inv = g * rsqrtf(v + EPS);
    float xv = x[((size_t)(b * 3 + c) * 224 + j) * 224 + t];
    xf[c] = (xv - m) * inv + bb;
  }
  float u[64];
  #pragma unroll
  for (int c = 0; c < 64; ++c) {
    float a = w1s[c * 3 + 0] * xf[0] + w1s[c * 3 + 1] * xf[1] + w1s[c * 3 + 2] * xf[2] + b1s[c];
    u[c] = fmaxf(a, 0.f);
  }
  size_t base = ((size_t)(b * 224 + t) * 224 + j) * 128;
  for (int o = 0; o < 64; ++o) {
    float acc = b2s[o];
    #pragma unroll
    for (int c = 0; c < 64; ++c) acc += w2s[o * 64 + c] * u[c];
    H0[base + o] = f2b(fmaxf(acc, 0.f));
  }
  for (int o = 0; o < 64; ++o) H0[base + 64 + o] = f2b(spa1[o * 224 + j]);
}

// ---------------------------------------------------------------------------
// K2: MFMA conv1x1 (templated Cin/Cout, DUAL interleaved for ILP)
// out = act(bn(w1@in1 [+ w2@in2] + bias)); weights bf16 hi/lo.
// Block 128x128, 4 waves of 64x64 (4x4 MFMA tiles).
// Optional transposed output out_t[(bt*Cout + c)*224 + j].
// ---------------------------------------------------------------------------
template <int CIN, int COUT, int DUAL, int WRITE_T>
__global__ __launch_bounds__(256, 3) void k_conv_mfma(
    const bf16* __restrict__ in1,
    const bf16* __restrict__ w1h, const bf16* __restrict__ w1l,
    const bf16* __restrict__ in2,
    const bf16* __restrict__ w2h, const bf16* __restrict__ w2l,
    const float* __restrict__ bias, const float* __restrict__ bn,
    int do_relu, bf16* __restrict__ out, bf16* __restrict__ out_t) {
  const int tid = threadIdx.x;
  const int w = tid >> 6, lane = tid & 63;
  const int l15 = lane & 15, q = lane >> 4;
  const int m0w = blockIdx.x * 128 + (w >> 1) * 64;
  const int n0w = blockIdx.y * 128 + (w & 1) * 64;
  f32x4 acc[4][4] = {};
  constexpr int NKS = CIN / 32;
  #pragma unroll 2
  for (int ks = 0; ks < NKS; ++ks) {
    const int ko = ks * 32 + q * 8;
    v8s a1[4], a2[4];
    #pragma unroll
    for (int i = 0; i < 4; ++i) {
      a1[i] = *(const v8s*)(in1 + (size_t)(m0w + i * 16 + l15) * CIN + ko);
      if (DUAL) a2[i] = *(const v8s*)(in2 + (size_t)(m0w + i * 16 + l15) * CIN + ko);
    }
    #pragma unroll
    for (int ns = 0; ns < 4; ++ns) {
      const size_t wrow = (size_t)(n0w + ns * 16 + l15) * CIN + ko;
      v8s bh = *(const v8s*)(w1h + wrow);
      v8s bl = *(const v8s*)(w1l + wrow);
      v8s ch, cl;
      if (DUAL) {
        ch = *(const v8s*)(w2h + wrow);
        cl = *(const v8s*)(w2l + wrow);
      }
      #pragma unroll
      for (int i = 0; i < 4; ++i) {
        acc[i][ns] = MFMA16(a1[i], bl, acc[i][ns]);
        acc[i][ns] = MFMA16(a1[i], bh, acc[i][ns]);
        if (DUAL) {
          acc[i][ns] = MFMA16(a2[i], cl, acc[i][ns]);
          acc[i][ns] = MFMA16(a2[i], ch, acc[i][ns]);
        }
      }
    }
  }
  #pragma unroll
  for (int ns = 0; ns < 4; ++ns) {
    const int oc = n0w + ns * 16 + l15;
    float sc = 1.f, sh = bias[oc];
    if (bn != nullptr) {
      float g = bn[oc], bb = bn[COUT + oc], m = bn[2 * COUT + oc], v = bn[3 * COUT + oc];
      sc = g * rsqrtf(v + EPS);
      sh = (sh - m) * sc + bb;
    }
    #pragma unroll
    for (int i = 0; i < 4; ++i) {
      const int mbase = m0w + i * 16 + q * 4;
      float vals[4];
      #pragma unroll
      for (int r = 0; r < 4; ++r) {
        float val = acc[i][ns][r] * sc + sh;
        if (do_relu) val = fmaxf(val, 0.f);
        vals[r] = val;
        out[(size_t)(mbase + r) * COUT + oc] = f2b(val);
      }
      if (WRITE_T) {
        const int bt = mbase / 224;  // 4 consecutive rows share bt (224 % 4 == 0)
        const int j = mbase - bt * 224;
        unsigned short s0 = __bfloat16_as_ushort(f2b(vals[0]));
        unsigned short s1 = __bfloat16_as_ushort(f2b(vals[1]));
        unsigned short s2 = __bfloat16_as_ushort(f2b(vals[2]));
        unsigned short s3 = __bfloat16_as_ushort(f2b(vals[3]));
        uint2 pk;
        pk.x = (unsigned int)s0 | ((unsigned int)s1 << 16);
        pk.y = (unsigned int)s2 | ((unsigned int)s3 << 16);
        *(uint2*)((unsigned short*)out_t + ((size_t)bt * COUT + oc) * 224 + j) = pk;
      }
    }
  }
}

// ---------------------------------------------------------------------------
// K2b: per-chunk transpose of H0c [bt*224+j][128] -> Ht [(bt*128)+c][224]
// ---------------------------------------------------------------------------
__global__ __launch_bounds__(256) void k_transpose128(
    const bf16* __restrict__ src, bf16* __restrict__ dst) {
  const int j0 = blockIdx.x * 32, c0 = blockIdx.y * 32, bt = blockIdx.z;
  __shared__ unsigned short ts[32][33];
  const int tid = threadIdx.x;
  {
    int r = tid >> 3, cg = (tid & 7) * 4;
    const unsigned short* sp =
        (const unsigned short*)src + ((size_t)(bt * 224) + j0 + r) * 128 + c0 + cg;
    uint2 u = *(const uint2*)sp;
    ts[r][cg + 0] = (unsigned short)(u.x & 0xffffu);
    ts[r][cg + 1] = (unsigned short)(u.x >> 16);
    ts[r][cg + 2] = (unsigned short)(u.y & 0xffffu);
    ts[r][cg + 3] = (unsigned short)(u.y >> 16);
  }
  __syncthreads();
  {
    int c = tid >> 3, jg = (tid & 7) * 4;
    uint2 o;
    o.x = (unsigned int)ts[jg + 0][c] | ((unsigned int)ts[jg + 1][c] << 16);
    o.y = (unsigned int)ts[jg + 2][c] | ((unsigned int)ts[jg + 3][c] << 16);
    *(uint2*)((unsigned short*)dst + ((size_t)(bt * 128) + c0 + c) * 224 + j0 + jg) = o;
  }
}

// ---------------------------------------------------------------------------
// K3: MFMA scores + softmax. A[bt*224+j][128], H[bt*224+k][128] ->
// G[bt][j][k] = softmax_k(A_j . H_k). Wave = 16 j-rows x all 224 k.
// ---------------------------------------------------------------------------
__global__ __launch_bounds__(256) void k_scores_mfma(
    const bf16* __restrict__ A, const bf16* __restrict__ H, bf16* __restrict__ G) {
  const int bt = blockIdx.y;
  const int w = threadIdx.x >> 6, lane = threadIdx.x & 63;
  const int mt = blockIdx.x * 4 + w;
  if (mt >= 14) return;
  const int l15 = lane & 15, q = lane >> 4;
  const int j0 = mt * 16;
  const bf16* Ab = A + (size_t)bt * 224 * 128;
  const bf16* Hb = H + (size_t)bt * 224 * 128;
  v8s a[4];
  #pragma unroll
  for (int ks = 0; ks < 4; ++ks)
    a[ks] = *(const v8s*)(Ab + (size_t)(j0 + l15) * 128 + ks * 32 + q * 8);
  f32x4 s[14];
  #pragma unroll 2
  for (int nt = 0; nt < 14; ++nt) {
    f32x4 acc = {0.f, 0.f, 0.f, 0.f};
    #pragma unroll
    for (int ks = 0; ks < 4; ++ks) {
      v8s b = *(const v8s*)(Hb + (size_t)(nt * 16 + l15) * 128 + ks * 32 + q * 8);
      acc = MFMA16(a[ks], b, acc);
    }
    s[nt] = acc;
  }
  bf16* Gb = G + ((size_t)bt * 224 + j0) * 224;
  #pragma unroll
  for (int r = 0; r < 4; ++r) {
    float mx = -1e30f;
    #pragma unroll
    for (int nt = 0; nt < 14; ++nt) mx = fmaxf(mx, s[nt][r]);
    mx = fmaxf(mx, __shfl_xor(mx, 1));
    mx = fmaxf(mx, __shfl_xor(mx, 2));
    mx = fmaxf(mx, __shfl_xor(mx, 4));
    mx = fmaxf(mx, __shfl_xor(mx, 8));
    float sum = 0.f;
    #pragma unroll
    for (int nt = 0; nt < 14; ++nt) {
      float e = __expf(s[nt][r] - mx);
      s[nt][r] = e;
      sum += e;
    }
    sum += __shfl_xor(sum, 1);
    sum += __shfl_xor(sum, 2);
    sum += __shfl_xor(sum, 4);
    sum += __shfl_xor(sum, 8);
    const float inv = 1.f / sum;
    const int jr = q * 4 + r;
    #pragma unroll
    for (int nt = 0; nt < 14; ++nt)
      Gb[(size_t)jr * 224 + nt * 16 + l15] = f2b(s[nt][r] * inv);
  }
}

// ---------------------------------------------------------------------------
// K4: MFMA apply (templated C): Y[bt*224+j][c] = sum_k G[bt][j][k]*Ht[bt][c][k]
// Wave = 32 j-rows x all C cols. Ht rows are k-contiguous (transposed H).
// ---------------------------------------------------------------------------
template <int C>
__global__ __launch_bounds__(256, 3) void k_apply_mfma(
    const bf16* __restrict__ G, const bf16* __restrict__ Ht,
    bf16* __restrict__ Y) {
  const int bt = blockIdx.y;
  const int w = threadIdx.x >> 6;
  const int p = blockIdx.x * 4 + w;
  if (p >= 7) return;
  const int lane = threadIdx.x & 63;
  const int l15 = lane & 15, q = lane >> 4;
  const int j0 = p * 32;
  const bf16* Gb = G + (size_t)bt * 224 * 224;
  const bf16* Hb = Ht + (size_t)bt * C * 224;
  bf16* Yb = Y + (size_t)bt * 224 * C;
  v8s a[2][7];
  #pragma unroll
  for (int h = 0; h < 2; ++h)
    #pragma unroll
    for (int ks = 0; ks < 7; ++ks)
      a[h][ks] = *(const v8s*)(Gb + (size_t)(j0 + h * 16 + l15) * 224 + ks * 32 + q * 8);
  constexpr int NNT = C / 16;
  #pragma unroll 2
  for (int nt = 0; nt < NNT; ++nt) {
    f32x4 acc0 = {0.f, 0.f, 0.f, 0.f};
    f32x4 acc1 = {0.f, 0.f, 0.f, 0.f};
    #pragma unroll
    for (int ks = 0; ks < 7; ++ks) {
      v8s b = *(const v8s*)(Hb + (size_t)(nt * 16 + l15) * 224 + ks * 32 + q * 8);
      acc0 = MFMA16(a[0][ks], b, acc0);
      acc1 = MFMA16(a[1][ks], b, acc1);
    }
    const int c = nt * 16 + l15;
    #pragma unroll
    for (int r = 0; r < 4; ++r) {
      Yb[(size_t)(j0 + q * 4 + r) * C + c] = f2b(acc0[r]);
      Yb[(size_t)(j0 + 16 + q * 4 + r) * C + c] = f2b(acc1[r]);
    }
  }
}

// ---------------------------------------------------------------------------
// K5: Hred[(b0 + bt/224)*224 + t, o] = max_j H3[bt,j,o] + tem1[o,t]
// ---------------------------------------------------------------------------
__global__ __launch_bounds__(256) void k_reduce(
    const bf16* __restrict__ H3, const float* __restrict__ tem1,
    float* __restrict__ Hred, int b0) {
  int bt = blockIdx.x;
  int o = threadIdx.x;
  int b = b0 + bt / 224;
  int t = bt % 224;
  const unsigned short* p = (const unsigned short*)(H3 + (size_t)bt * 224 * 256 + o);
  float mx = -1e30f;
  for (int j = 0; j < 224; ++j) mx = fmaxf(mx, bfu(p[j * 256]));
  Hred[((size_t)b * 224 + t) * 256 + o] = mx + tem1[o * 224 + t];
}

// ---------------------------------------------------------------------------
// K6a: adaptive max pool 224 -> 20 over t. Grid (4,20), block 256 (c).
// ---------------------------------------------------------------------------
__global__ __launch_bounds__(256) void k_head_a(
    const float* __restrict__ Hred, float* __restrict__ Hm) {
  int b = blockIdx.x, i = blockIdx.y, c = threadIdx.x;
  int s = (i * 224) / 20, e = ((i + 1) * 224 + 19) / 20;
  float mx = -1e30f;
  for (int t = s; t < e; ++t) mx = fmaxf(mx, Hred[((size_t)b * 224 + t) * 256 + c]);
  Hm[((size_t)b * 20 + i) * 256 + c] = mx;
}

// ---------------------------------------------------------------------------
// K6b: loc1 width-3 conv + bn + relu. Grid (4,20), block 256 (o).
// ---------------------------------------------------------------------------
__global__ __launch_bounds__(256) void k_head_b(
    const float* __restrict__ Hm, const float* __restrict__ loc1_w,
    const float* __restrict__ loc1_b, const float* __restrict__ loc1_bn,
    float* __restrict__ Z1) {
  int b = blockIdx.x, r = blockIdx.y;
  __shared__ float hs[3 * 256];
  int tid = threadIdx.x;
  for (int idx = tid; idx < 768; idx += 256) {
    int dx = idx >> 8, c = idx & 255;
    int u = r + dx - 1;
    hs[idx] = (u >= 0 && u < 20) ? Hm[((size_t)b * 20 + u) * 256 + c] : 0.f;
  }
  __syncthreads();
  int o = tid;
  float acc = loc1_b[o];
  const float* wp = loc1_w + (size_t)o * 768;
  #pragma unroll 4
  for (int c = 0; c < 256; ++c) {
    acc += wp[c * 3 + 0] * hs[c] + wp[c * 3 + 1] * hs[256 + c] + wp[c * 3 + 2] * hs[512 + c];
  }
  float g = loc1_bn[o], bb = loc1_bn[256 + o], m = loc1_bn[512 + o], v = loc1_bn[768 + o];
  float sc = g * rsqrtf(v + EPS);
  Z1[((size_t)b * 20 + r) * 256 + o] = fmaxf((acc - m) * sc + bb, 0.f);
}

// ---------------------------------------------------------------------------
// K6c: loc2 + bn + relu + max over 20 positions. Grid 4, block 512 (o2).
// ---------------------------------------------------------------------------
__global__ __launch_bounds__(512) void k_head_c(
    const float* __restrict__ Z1, const float* __restrict__ loc2_w,
    const float* __restrict__ loc2_b, const float* __restrict__ loc2_bn,
    float* __restrict__ out) {
  int b = blockIdx.x;
  int tid = threadIdx.x;
  __shared__ float zs[20 * 256];
  for (int idx = tid; idx < 5120; idx += 512) zs[idx] = Z1[(size_t)b * 5120 + idx];
  __syncthreads();
  int o2 = tid;
  float acc[20];
  float bi = loc2_b[o2];
  #pragma unroll
  for (int r = 0; r < 20; ++r) acc[r] = bi;
  const float* wp = loc2_w + (size_t)o2 * 256;
  for (int c = 0; c < 256; ++c) {
    float wv = wp[c];
    #pragma unroll
    for (int r = 0; r < 20; ++r) acc[r] += wv * zs[r * 256 + c];
  }
  float g = loc2_bn[o2], bb = loc2_bn[512 + o2], m = loc2_bn[1024 + o2], v = loc2_bn[1536 + o2];
  float sc = g * rsqrtf(v + EPS);
  float best = -1e30f;
  #pragma unroll
  for (int r = 0; r < 20; ++r) best = fmaxf(best, fmaxf((acc[r] - m) * sc + bb, 0.f));
  out[(size_t)b * 512 + o2] = best;
}

// ---------------------------------------------------------------------------
extern "C" void kernel_launch(void* const* d_in, const int* in_sizes, int n_in,
                              void* d_out, int out_size, void* d_ws, size_t ws_size,
                              hipStream_t stream) {
  const float* x       = (const float*)d_in[0];
  const float* je1_w   = (const float*)d_in[1];
  const float* je1_b   = (const float*)d_in[2];
  const float* je2_w   = (const float*)d_in[3];
  const float* je2_b   = (const float*)d_in[4];
  const float* se1_w   = (const float*)d_in[5];
  const float* se1_b   = (const float*)d_in[6];
  const float* se2_w   = (const float*)d_in[7];
  const float* se2_b   = (const float*)d_in[8];
  const float* te1_w   = (const float*)d_in[9];
  const float* te1_b   = (const float*)d_in[10];
  const float* te2_w   = (const float*)d_in[11];
  const float* te2_b   = (const float*)d_in[12];
  const float* g1_w    = (const float*)d_in[13];
  const float* g1_b    = (const float*)d_in[14];
  const float* g2_w    = (const float*)d_in[15];
  const float* gcn1_w  = (const float*)d_in[17];
  const float* gcn1_w1 = (const float*)d_in[18];
  const float* gcn1_b  = (const float*)d_in[19];
  const float* gcn2_w  = (const float*)d_in[20];
  const float* gcn2_w1 = (const float*)d_in[21];
  const float* gcn2_b  = (const float*)d_in[22];
  const float* gcn3_w  = (const float*)d_in[23];
  const float* gcn3_w1 = (const float*)d_in[24];
  const float* gcn3_b  = (const float*)d_in[25];
  const float* loc1_w  = (const float*)d_in[26];
  const float* loc1_b  = (const float*)d_in[27];
  const float* loc2_w  = (const float*)d_in[28];
  const float* loc2_b  = (const float*)d_in[29];
  const float* bn0     = (const float*)d_in[30];
  const float* gcn1_bn = (const float*)d_in[31];
  const float* gcn2_bn = (const float*)d_in[32];
  const float* gcn3_bn = (const float*)d_in[33];
  const float* loc1_bn = (const float*)d_in[34];
  const float* loc2_bn = (const float*)d_in[35];
  float* out = (float*)d_out;
  (void)in_sizes; (void)n_in; (void)out_size;

  auto al = [](size_t b) -> size_t { return (b + 255) & ~(size_t)255; };
  // Fixed small buffers + full H0 + per-chunk requirement for S batches/chunk.
  const size_t fixedB = al(256 * 224 * 4) + al(64 * 224 * 4) + al(128 * 128 * 2) * 2 +
                        al(128 * 4) + al(458752 * 2) + al(4 * 20 * 256 * 4) * 2 +
                        al(896 * 256 * 4);
  const size_t H0B = al((size_t)200704 * 128 * 2);
  auto perS = [&](int S) -> size_t {
    size_t Mc = (size_t)50176 * S;
    return al(Mc * 256 * 2) * 3 + al(Mc * 224 * 2);
  };
  int S = (ws_size >= fixedB + H0B + perS(2)) ? 2 : 1;
  const size_t Mc = (size_t)50176 * S;  // positions per chunk
  const int nChunk = 4 / S;

  char* ws = (char*)d_ws;
  size_t off = 0;
  auto take = [&](size_t bytes) -> char* {
    char* p = ws + off;
    off += (bytes + 255) & ~(size_t)255;
    return p;
  };
  float* tem1 = (float*)take(256 * 224 * 4);
  float* spa1 = (float*)take(64 * 224 * 4);
  bf16* WmH   = (bf16*)take(128 * 128 * 2);
  bf16* WmL   = (bf16*)take(128 * 128 * 2);
  float* dvec = (float*)take(128 * 4);
  bf16* wb    = (bf16*)take(458752 * 2);  // gcn weights hi/lo packed
  float* Hm   = (float*)take(4 * 20 * 256 * 4);
  float* Z1   = (float*)take(4 * 20 * 256 * 4);
  float* Hred = (float*)take(896 * 256 * 4);
  bf16* H0 = (bf16*)take((size_t)200704 * 128 * 2);  // full H0 [M,128]
  bf16* YZ = (bf16*)take(Mc * 256 * 2);   // Y half / Z half; Y3 spans both
  bf16* Wb = (bf16*)take(Mc * 256 * 2);   // H2 row-major
  bf16* HtV = (bf16*)take(Mc * 256 * 2);  // Ht (H0t/H1t/H2t) then H3 (conv3 out)
  bf16* Gm = (bf16*)take(Mc * 224 * 2);   // softmax probs per chunk
  bf16* Yr = YZ;
  bf16* Zr = YZ + Mc * 128;

  bf16* g1w_h  = wb;           bf16* g1w_l  = wb + 16384;
  bf16* g1w1_h = wb + 32768;   bf16* g1w1_l = wb + 49152;
  bf16* g2w_h  = wb + 65536;   bf16* g2w_l  = wb + 98304;
  bf16* g2w1_h = wb + 131072;  bf16* g2w1_l = wb + 163840;
  bf16* g3w_h  = wb + 196608;  bf16* g3w_l  = wb + 262144;
  bf16* g3w1_h = wb + 327680;  bf16* g3w1_l = wb + 393216;

  k_small<<<280, 256, 0, stream>>>(te1_w, te1_b, te2_w, te2_b,
                                   se1_w, se1_b, se2_w, se2_b, tem1, spa1);
  k_wm<<<64, 256, 0, stream>>>(g1_w, g2_w, g1_b, WmH, WmL, dvec);
  k_wcvt<<<896, 256, 0, stream>>>(gcn1_w, gcn1_w1, gcn2_w, gcn2_w1, gcn3_w, gcn3_w1, wb);
  k_h0<<<896, 256, 0, stream>>>(x, bn0, je1_w, je1_b, je2_w, je2_b, spa1, H0);

  for (int cb = 0; cb < nChunk; ++cb) {
    const bf16* H0c = H0 + (size_t)cb * Mc * 128;
    // A = H0c @ Wm^T + dvec  (fused q/k)
    k_conv_mfma<128, 128, 0, 0><<<dim3(392 * S, 1), 256, 0, stream>>>(
        H0c, WmH, WmL, nullptr, nullptr, nullptr, dvec, nullptr, 0, Yr, nullptr);
    // H0t for apply1
    k_transpose128<<<dim3(7, 4, 224 * S), 256, 0, stream>>>(H0c, HtV);
    // scores + softmax
    k_scores_mfma<<<dim3(4, 224 * S), 256, 0, stream>>>(Yr, H0c, Gm);
    // gcn1
    k_apply_mfma<128><<<dim3(2, 224 * S), 256, 0, stream>>>(Gm, HtV, Yr);
    k_conv_mfma<128, 128, 1, 1><<<dim3(392 * S, 1), 256, 0, stream>>>(
        Yr, g1w_h, g1w_l, H0c, g1w1_h, g1w1_l, gcn1_b, gcn1_bn, 1, Zr, HtV);
    // gcn2
    k_apply_mfma<128><<<dim3(2, 224 * S), 256, 0, stream>>>(Gm, HtV, Yr);
    k_conv_mfma<128, 256, 1, 1><<<dim3(392 * S, 2), 256, 0, stream>>>(
        Yr, g2w_h, g2w_l, Zr, g2w1_h, g2w1_l, gcn2_b, gcn2_bn, 1, Wb, HtV);
    // gcn3
    k_apply_mfma<256><<<dim3(2, 224 * S), 256, 0, stream>>>(Gm, HtV, YZ);
    k_conv_mfma<256, 256, 1, 0><<<dim3(392 * S, 2), 256, 0, stream>>>(
        YZ, g3w_h, g3w_l, Wb, g3w1_h, g3w1_l, gcn3_b, gcn3_bn, 1, HtV, nullptr);
    // + tem1, max over j
    k_reduce<<<224 * S, 256, 0, stream>>>(HtV, tem1, Hred, cb * S);
  }
  k_head_a<<<dim3(4, 20), 256, 0, stream>>>(Hred, Hm);
  k_head_b<<<dim3(4, 20), 256, 0, stream>>>(Hm, loc1_w, loc1_b, loc1_bn, Z1);
  k_head_c<<<4, 512, 0, stream>>>(Z1, loc2_w, loc2_b, loc2_bn, out);
}

// Round 5
// 1715.047 us; speedup vs baseline: 1.1119x; 1.1119x over previous
//
#include <hip/hip_runtime.h>
#include <hip/hip_bf16.h>

typedef __hip_bfloat16 bf16;
typedef __attribute__((ext_vector_type(8))) short v8s;
typedef __attribute__((ext_vector_type(4))) float f32x4;
#define EPS 1e-5f
#define MFMA16(a, b, c) __builtin_amdgcn_mfma_f32_16x16x32_bf16(a, b, c, 0, 0, 0)

__device__ __forceinline__ float bfu(unsigned int s) {
  union { unsigned int u; float f; } c; c.u = s << 16; return c.f;
}
__device__ __forceinline__ bf16 f2b(float v) { return __float2bfloat16(v); }

// ---------------------------------------------------------------------------
// K0: tem1 (256x224) and spa1 (64x224) closed-form tables
// ---------------------------------------------------------------------------
__global__ __launch_bounds__(256) void k_small(
    const float* __restrict__ te1_w, const float* __restrict__ te1_b,
    const float* __restrict__ te2_w, const float* __restrict__ te2_b,
    const float* __restrict__ se1_w, const float* __restrict__ se1_b,
    const float* __restrict__ se2_w, const float* __restrict__ se2_b,
    float* __restrict__ tem1, float* __restrict__ spa1) {
  int idx = blockIdx.x * 256 + threadIdx.x;
  if (idx >= (256 + 64) * 224) return;
  int o = idx / 224, t = idx % 224;
  if (o < 256) {
    float acc = te2_b[o];
    for (int c = 0; c < 64; ++c) {
      float u = fmaxf(te1_w[c * 224 + t] + te1_b[c], 0.f);
      acc += te2_w[o * 64 + c] * u;
    }
    tem1[o * 224 + t] = fmaxf(acc, 0.f);
  } else {
    int oo = o - 256;
    float acc = se2_b[oo];
    for (int c = 0; c < 64; ++c) {
      float u = fmaxf(se1_w[c * 224 + t] + se1_b[c], 0.f);
      acc += se2_w[oo * 64 + c] * u;
    }
    spa1[oo * 224 + t] = fmaxf(acc, 0.f);
  }
}

// ---------------------------------------------------------------------------
// K0b: Wm = g1^T g2 fused attention matrix (bf16 hi/lo), dvec = g2^T b1
// ---------------------------------------------------------------------------
__global__ __launch_bounds__(256) void k_wm(
    const float* __restrict__ g1_w, const float* __restrict__ g2_w,
    const float* __restrict__ g1_b, bf16* __restrict__ WmH, bf16* __restrict__ WmL,
    float* __restrict__ dvec) {
  int idx = blockIdx.x * 256 + threadIdx.x;
  if (idx >= 128 * 128) return;
  int o = idx >> 7, c = idx & 127;
  float acc = 0.f;
  for (int t = 0; t < 256; ++t) acc += g1_w[t * 128 + c] * g2_w[t * 128 + o];
  bf16 hi = f2b(acc);
  WmH[o * 128 + c] = hi;
  WmL[o * 128 + c] = f2b(acc - __bfloat162float(hi));
  if (c == 0) {
    float d = 0.f;
    for (int t = 0; t < 256; ++t) d += g2_w[t * 128 + o] * g1_b[t];
    dvec[o] = d;
  }
}

// ---------------------------------------------------------------------------
// K0c: convert the 6 gcn weights to bf16 hi/lo pairs (packed buffer)
// ---------------------------------------------------------------------------
__global__ __launch_bounds__(256) void k_wcvt(
    const float* __restrict__ g1w, const float* __restrict__ g1w1,
    const float* __restrict__ g2w, const float* __restrict__ g2w1,
    const float* __restrict__ g3w, const float* __restrict__ g3w1,
    bf16* __restrict__ dst) {
  int idx = blockIdx.x * 256 + threadIdx.x;
  const float* src; size_t base; int off; int sz;
  if (idx < 16384)        { src = g1w;  base = 0;      off = idx;          sz = 16384; }
  else if (idx < 32768)   { src = g1w1; base = 32768;  off = idx - 16384;  sz = 16384; }
  else if (idx < 65536)   { src = g2w;  base = 65536;  off = idx - 32768;  sz = 32768; }
  else if (idx < 98304)   { src = g2w1; base = 131072; off = idx - 65536;  sz = 32768; }
  else if (idx < 163840)  { src = g3w;  base = 196608; off = idx - 98304;  sz = 65536; }
  else if (idx < 229376)  { src = g3w1; base = 327680; off = idx - 163840; sz = 65536; }
  else return;
  float v = src[off];
  bf16 hi = f2b(v);
  dst[base + off] = hi;
  dst[base + sz + off] = f2b(v - __bfloat162float(hi));
}

// ---------------------------------------------------------------------------
// K1: bn0 + je1 + relu + je2 + relu -> H0[b,t,j,c]
// ---------------------------------------------------------------------------
__global__ __launch_bounds__(256) void k_h0(
    const float* __restrict__ x, const float* __restrict__ bn0,
    const float* __restrict__ je1_w, const float* __restrict__ je1_b,
    const float* __restrict__ je2_w, const float* __restrict__ je2_b,
    const float* __restrict__ spa1, bf16* __restrict__ H0) {
  int bj = blockIdx.x;
  int b = bj / 224, j = bj % 224;
  __shared__ float w1s[192], b1s[64], w2s[4096], b2s[64];
  int tid = threadIdx.x;
  for (int i = tid; i < 192; i += 256) w1s[i] = je1_w[i];
  for (int i = tid; i < 64; i += 256) { b1s[i] = je1_b[i]; b2s[i] = je2_b[i]; }
  for (int i = tid; i < 4096; i += 256) w2s[i] = je2_w[i];
  __syncthreads();
  int t = tid;
  if (t >= 224) return;
  float xf[3];
  #pragma unroll
  for (int c = 0; c < 3; ++c) {
    int ch = c * 224 + j;
    float g = bn0[ch], bb = bn0[672 + ch], m = bn0[2 * 672 + ch], v = bn0[3 * 672 + ch];
    float inv = g * rsqrtf(v + EPS);
    float xv = x[((size_t)(b * 3 + c) * 224 + j) * 224 + t];
    xf[c] = (xv - m) * inv + bb;
  }
  float u[64];
  #pragma unroll
  for (int c = 0; c < 64; ++c) {
    float a = w1s[c * 3 + 0] * xf[0] + w1s[c * 3 + 1] * xf[1] + w1s[c * 3 + 2] * xf[2] + b1s[c];
    u[c] = fmaxf(a, 0.f);
  }
  size_t base = ((size_t)(b * 224 + t) * 224 + j) * 128;
  for (int o = 0; o < 64; ++o) {
    float acc = b2s[o];
    #pragma unroll
    for (int c = 0; c < 64; ++c) acc += w2s[o * 64 + c] * u[c];
    H0[base + o] = f2b(fmaxf(acc, 0.f));
  }
  for (int o = 0; o < 64; ++o) H0[base + 64 + o] = f2b(spa1[o * 224 + j]);
}

// ---------------------------------------------------------------------------
// K2: MFMA conv1x1. Block tile 64(M) x 128(N): 4 waves of 64x32.
// out = act(bn(w1@in1 [+ w2@in2] + bias)); weights bf16 hi/lo.
// Full K-unroll so the compiler software-pipelines the independent loads.
// Optional transposed output out_t[(bt*Cout + c)*224 + j].
// ---------------------------------------------------------------------------
template <int CIN, int COUT, int DUAL, int WRITE_T>
__global__ __launch_bounds__(256, 3) void k_conv_mfma(
    const bf16* __restrict__ in1,
    const bf16* __restrict__ w1h, const bf16* __restrict__ w1l,
    const bf16* __restrict__ in2,
    const bf16* __restrict__ w2h, const bf16* __restrict__ w2l,
    const float* __restrict__ bias, const float* __restrict__ bn,
    int do_relu, bf16* __restrict__ out, bf16* __restrict__ out_t) {
  const int tid = threadIdx.x;
  const int w = tid >> 6, lane = tid & 63;
  const int l15 = lane & 15, q = lane >> 4;
  const int m0 = blockIdx.x * 64;
  const int n0w = blockIdx.y * 128 + w * 32;
  f32x4 acc[4][2] = {};
  constexpr int NKS = CIN / 32;
  #pragma unroll
  for (int ks = 0; ks < NKS; ++ks) {
    const int ko = ks * 32 + q * 8;
    v8s a1[4], a2[4], wh[4], wl[4];
    #pragma unroll
    for (int i = 0; i < 4; ++i) {
      a1[i] = *(const v8s*)(in1 + (size_t)(m0 + i * 16 + l15) * CIN + ko);
      if (DUAL) a2[i] = *(const v8s*)(in2 + (size_t)(m0 + i * 16 + l15) * CIN + ko);
    }
    #pragma unroll
    for (int ns = 0; ns < 2; ++ns) {
      const size_t wrow = (size_t)(n0w + ns * 16 + l15) * CIN + ko;
      wh[ns] = *(const v8s*)(w1h + wrow);
      wl[ns] = *(const v8s*)(w1l + wrow);
      if (DUAL) {
        wh[2 + ns] = *(const v8s*)(w2h + wrow);
        wl[2 + ns] = *(const v8s*)(w2l + wrow);
      }
    }
    #pragma unroll
    for (int ns = 0; ns < 2; ++ns)
      #pragma unroll
      for (int i = 0; i < 4; ++i) {
        acc[i][ns] = MFMA16(a1[i], wl[ns], acc[i][ns]);
        acc[i][ns] = MFMA16(a1[i], wh[ns], acc[i][ns]);
        if (DUAL) {
          acc[i][ns] = MFMA16(a2[i], wl[2 + ns], acc[i][ns]);
          acc[i][ns] = MFMA16(a2[i], wh[2 + ns], acc[i][ns]);
        }
      }
  }
  #pragma unroll
  for (int ns = 0; ns < 2; ++ns) {
    const int oc = n0w + ns * 16 + l15;
    float sc = 1.f, sh = bias[oc];
    if (bn != nullptr) {
      float g = bn[oc], bb = bn[COUT + oc], m = bn[2 * COUT + oc], v = bn[3 * COUT + oc];
      sc = g * rsqrtf(v + EPS);
      sh = (sh - m) * sc + bb;
    }
    #pragma unroll
    for (int i = 0; i < 4; ++i) {
      const int mbase = m0 + i * 16 + q * 4;
      float vals[4];
      #pragma unroll
      for (int r = 0; r < 4; ++r) {
        float val = acc[i][ns][r] * sc + sh;
        if (do_relu) val = fmaxf(val, 0.f);
        vals[r] = val;
        out[(size_t)(mbase + r) * COUT + oc] = f2b(val);
      }
      if (WRITE_T) {
        const int bt = mbase / 224;  // 4-row store group stays in one bt (224%4==0)
        const int j = mbase - bt * 224;
        unsigned short s0 = __bfloat16_as_ushort(f2b(vals[0]));
        unsigned short s1 = __bfloat16_as_ushort(f2b(vals[1]));
        unsigned short s2 = __bfloat16_as_ushort(f2b(vals[2]));
        unsigned short s3 = __bfloat16_as_ushort(f2b(vals[3]));
        uint2 pk;
        pk.x = (unsigned int)s0 | ((unsigned int)s1 << 16);
        pk.y = (unsigned int)s2 | ((unsigned int)s3 << 16);
        *(uint2*)((unsigned short*)out_t + ((size_t)bt * COUT + oc) * 224 + j) = pk;
      }
    }
  }
}

// ---------------------------------------------------------------------------
// K2b: per-chunk transpose of H0c [bt*224+j][128] -> Ht [(bt*128)+c][224]
// ---------------------------------------------------------------------------
__global__ __launch_bounds__(256) void k_transpose128(
    const bf16* __restrict__ src, bf16* __restrict__ dst) {
  const int j0 = blockIdx.x * 32, c0 = blockIdx.y * 32, bt = blockIdx.z;
  __shared__ unsigned short ts[32][33];
  const int tid = threadIdx.x;
  {
    int r = tid >> 3, cg = (tid & 7) * 4;
    const unsigned short* sp =
        (const unsigned short*)src + ((size_t)(bt * 224) + j0 + r) * 128 + c0 + cg;
    uint2 u = *(const uint2*)sp;
    ts[r][cg + 0] = (unsigned short)(u.x & 0xffffu);
    ts[r][cg + 1] = (unsigned short)(u.x >> 16);
    ts[r][cg + 2] = (unsigned short)(u.y & 0xffffu);
    ts[r][cg + 3] = (unsigned short)(u.y >> 16);
  }
  __syncthreads();
  {
    int c = tid >> 3, jg = (tid & 7) * 4;
    uint2 o;
    o.x = (unsigned int)ts[jg + 0][c] | ((unsigned int)ts[jg + 1][c] << 16);
    o.y = (unsigned int)ts[jg + 2][c] | ((unsigned int)ts[jg + 3][c] << 16);
    *(uint2*)((unsigned short*)dst + ((size_t)(bt * 128) + c0 + c) * 224 + j0 + jg) = o;
  }
}

// ---------------------------------------------------------------------------
// K3: MFMA scores + softmax. A[bt*224+j][128], H[bt*224+k][128] ->
// G[bt][j][k] = softmax_k(A_j . H_k). Wave = 16 j-rows x all 224 k.
// ---------------------------------------------------------------------------
__global__ __launch_bounds__(256, 3) void k_scores_mfma(
    const bf16* __restrict__ A, const bf16* __restrict__ H, bf16* __restrict__ G) {
  const int bt = blockIdx.y;
  const int w = threadIdx.x >> 6, lane = threadIdx.x & 63;
  const int mt = blockIdx.x * 4 + w;
  if (mt >= 14) return;
  const int l15 = lane & 15, q = lane >> 4;
  const int j0 = mt * 16;
  const bf16* Ab = A + (size_t)bt * 224 * 128;
  const bf16* Hb = H + (size_t)bt * 224 * 128;
  v8s a[4];
  #pragma unroll
  for (int ks = 0; ks < 4; ++ks)
    a[ks] = *(const v8s*)(Ab + (size_t)(j0 + l15) * 128 + ks * 32 + q * 8);
  f32x4 s[14];
  #pragma unroll
  for (int nt = 0; nt < 14; ++nt) {
    f32x4 acc = {0.f, 0.f, 0.f, 0.f};
    #pragma unroll
    for (int ks = 0; ks < 4; ++ks) {
      v8s b = *(const v8s*)(Hb + (size_t)(nt * 16 + l15) * 128 + ks * 32 + q * 8);
      acc = MFMA16(a[ks], b, acc);
    }
    s[nt] = acc;
  }
  bf16* Gb = G + ((size_t)bt * 224 + j0) * 224;
  #pragma unroll
  for (int r = 0; r < 4; ++r) {
    float mx = -1e30f;
    #pragma unroll
    for (int nt = 0; nt < 14; ++nt) mx = fmaxf(mx, s[nt][r]);
    mx = fmaxf(mx, __shfl_xor(mx, 1));
    mx = fmaxf(mx, __shfl_xor(mx, 2));
    mx = fmaxf(mx, __shfl_xor(mx, 4));
    mx = fmaxf(mx, __shfl_xor(mx, 8));
    float sum = 0.f;
    #pragma unroll
    for (int nt = 0; nt < 14; ++nt) {
      float e = __expf(s[nt][r] - mx);
      s[nt][r] = e;
      sum += e;
    }
    sum += __shfl_xor(sum, 1);
    sum += __shfl_xor(sum, 2);
    sum += __shfl_xor(sum, 4);
    sum += __shfl_xor(sum, 8);
    const float inv = 1.f / sum;
    const int jr = q * 4 + r;
    #pragma unroll
    for (int nt = 0; nt < 14; ++nt)
      Gb[(size_t)jr * 224 + nt * 16 + l15] = f2b(s[nt][r] * inv);
  }
}

// ---------------------------------------------------------------------------
// K4: MFMA apply: Y[bt*224+j][c] = sum_k G[bt][j][k]*Ht[bt][c][k]
// Grid (7, bt). Block = 4 waves sharing the same 32 j-rows, C split 4 ways.
// ---------------------------------------------------------------------------
template <int C>
__global__ __launch_bounds__(256, 3) void k_apply_mfma(
    const bf16* __restrict__ G, const bf16* __restrict__ Ht,
    bf16* __restrict__ Y) {
  const int bt = blockIdx.y;
  const int w = threadIdx.x >> 6;
  const int lane = threadIdx.x & 63;
  const int l15 = lane & 15, q = lane >> 4;
  const int j0 = blockIdx.x * 32;
  const bf16* Gb = G + (size_t)bt * 224 * 224;
  const bf16* Hb = Ht + (size_t)bt * C * 224;
  bf16* Yb = Y + (size_t)bt * 224 * C;
  v8s a[2][7];
  #pragma unroll
  for (int h = 0; h < 2; ++h)
    #pragma unroll
    for (int ks = 0; ks < 7; ++ks)
      a[h][ks] = *(const v8s*)(Gb + (size_t)(j0 + h * 16 + l15) * 224 + ks * 32 + q * 8);
  constexpr int NPW = C / 64;  // nt per wave
  #pragma unroll
  for (int u = 0; u < NPW; ++u) {
    const int nt = w * NPW + u;
    f32x4 acc0 = {0.f, 0.f, 0.f, 0.f};
    f32x4 acc1 = {0.f, 0.f, 0.f, 0.f};
    #pragma unroll
    for (int ks = 0; ks < 7; ++ks) {
      v8s b = *(const v8s*)(Hb + (size_t)(nt * 16 + l15) * 224 + ks * 32 + q * 8);
      acc0 = MFMA16(a[0][ks], b, acc0);
      acc1 = MFMA16(a[1][ks], b, acc1);
    }
    const int c = nt * 16 + l15;
    #pragma unroll
    for (int r = 0; r < 4; ++r) {
      Yb[(size_t)(j0 + q * 4 + r) * C + c] = f2b(acc0[r]);
      Yb[(size_t)(j0 + 16 + q * 4 + r) * C + c] = f2b(acc1[r]);
    }
  }
}

// ---------------------------------------------------------------------------
// K5: partial max over j (32 rows per block) -> atomicMax into Hred (>=0)
// ---------------------------------------------------------------------------
__global__ __launch_bounds__(256) void k_reduce(
    const bf16* __restrict__ H3, float* __restrict__ Hred, int row0) {
  int t = blockIdx.x;
  int jb = blockIdx.y;
  int o = threadIdx.x;
  const unsigned short* p =
      (const unsigned short*)(H3 + ((size_t)t * 224 + jb * 32) * 256 + o);
  float mx = 0.f;
  #pragma unroll 8
  for (int j = 0; j < 32; ++j) mx = fmaxf(mx, bfu(p[(size_t)j * 256]));
  atomicMax((unsigned int*)&Hred[(size_t)(row0 + t) * 256 + o], __float_as_uint(mx));
}

// ---------------------------------------------------------------------------
// K6a: adaptive max pool 224 -> 20 over t, adding tem1[c,t]. Grid (4,20).
// ---------------------------------------------------------------------------
__global__ __launch_bounds__(256) void k_head_a(
    const float* __restrict__ Hred, const float* __restrict__ tem1,
    float* __restrict__ Hm) {
  int b = blockIdx.x, i = blockIdx.y, c = threadIdx.x;
  int s = (i * 224) / 20, e = ((i + 1) * 224 + 19) / 20;
  float mx = -1e30f;
  for (int t = s; t < e; ++t)
    mx = fmaxf(mx, Hred[((size_t)b * 224 + t) * 256 + c] + tem1[c * 224 + t]);
  Hm[((size_t)b * 20 + i) * 256 + c] = mx;
}

// ---------------------------------------------------------------------------
// K6b: loc1 width-3 conv + bn + relu. Grid (4,20), block 256 (o).
// ---------------------------------------------------------------------------
__global__ __launch_bounds__(256) void k_head_b(
    const float* __restrict__ Hm, const float* __restrict__ loc1_w,
    const float* __restrict__ loc1_b, const float* __restrict__ loc1_bn,
    float* __restrict__ Z1) {
  int b = blockIdx.x, r = blockIdx.y;
  __shared__ float hs[3 * 256];
  int tid = threadIdx.x;
  for (int idx = tid; idx < 768; idx += 256) {
    int dx = idx >> 8, c = idx & 255;
    int u = r + dx - 1;
    hs[idx] = (u >= 0 && u < 20) ? Hm[((size_t)b * 20 + u) * 256 + c] : 0.f;
  }
  __syncthreads();
  int o = tid;
  float acc = loc1_b[o];
  const float* wp = loc1_w + (size_t)o * 768;
  #pragma unroll 4
  for (int c = 0; c < 256; ++c) {
    acc += wp[c * 3 + 0] * hs[c] + wp[c * 3 + 1] * hs[256 + c] + wp[c * 3 + 2] * hs[512 + c];
  }
  float g = loc1_bn[o], bb = loc1_bn[256 + o], m = loc1_bn[512 + o], v = loc1_bn[768 + o];
  float sc = g * rsqrtf(v + EPS);
  Z1[((size_t)b * 20 + r) * 256 + o] = fmaxf((acc - m) * sc + bb, 0.f);
}

// ---------------------------------------------------------------------------
// K6c: loc2 + bn + relu + max over 20 positions. Grid 4, block 512 (o2).
// ---------------------------------------------------------------------------
__global__ __launch_bounds__(512) void k_head_c(
    const float* __restrict__ Z1, const float* __restrict__ loc2_w,
    const float* __restrict__ loc2_b, const float* __restrict__ loc2_bn,
    float* __restrict__ out) {
  int b = blockIdx.x;
  int tid = threadIdx.x;
  __shared__ float zs[20 * 256];
  for (int idx = tid; idx < 5120; idx += 512) zs[idx] = Z1[(size_t)b * 5120 + idx];
  __syncthreads();
  int o2 = tid;
  float acc[20];
  float bi = loc2_b[o2];
  #pragma unroll
  for (int r = 0; r < 20; ++r) acc[r] = bi;
  const float* wp = loc2_w + (size_t)o2 * 256;
  for (int c = 0; c < 256; ++c) {
    float wv = wp[c];
    #pragma unroll
    for (int r = 0; r < 20; ++r) acc[r] += wv * zs[r * 256 + c];
  }
  float g = loc2_bn[o2], bb = loc2_bn[512 + o2], m = loc2_bn[1024 + o2], v = loc2_bn[1536 + o2];
  float sc = g * rsqrtf(v + EPS);
  float best = -1e30f;
  #pragma unroll
  for (int r = 0; r < 20; ++r) best = fmaxf(best, fmaxf((acc[r] - m) * sc + bb, 0.f));
  out[(size_t)b * 512 + o2] = best;
}

// ---------------------------------------------------------------------------
extern "C" void kernel_launch(void* const* d_in, const int* in_sizes, int n_in,
                              void* d_out, int out_size, void* d_ws, size_t ws_size,
                              hipStream_t stream) {
  const float* x       = (const float*)d_in[0];
  const float* je1_w   = (const float*)d_in[1];
  const float* je1_b   = (const float*)d_in[2];
  const float* je2_w   = (const float*)d_in[3];
  const float* je2_b   = (const float*)d_in[4];
  const float* se1_w   = (const float*)d_in[5];
  const float* se1_b   = (const float*)d_in[6];
  const float* se2_w   = (const float*)d_in[7];
  const float* se2_b   = (const float*)d_in[8];
  const float* te1_w   = (const float*)d_in[9];
  const float* te1_b   = (const float*)d_in[10];
  const float* te2_w   = (const float*)d_in[11];
  const float* te2_b   = (const float*)d_in[12];
  const float* g1_w    = (const float*)d_in[13];
  const float* g1_b    = (const float*)d_in[14];
  const float* g2_w    = (const float*)d_in[15];
  const float* gcn1_w  = (const float*)d_in[17];
  const float* gcn1_w1 = (const float*)d_in[18];
  const float* gcn1_b  = (const float*)d_in[19];
  const float* gcn2_w  = (const float*)d_in[20];
  const float* gcn2_w1 = (const float*)d_in[21];
  const float* gcn2_b  = (const float*)d_in[22];
  const float* gcn3_w  = (const float*)d_in[23];
  const float* gcn3_w1 = (const float*)d_in[24];
  const float* gcn3_b  = (const float*)d_in[25];
  const float* loc1_w  = (const float*)d_in[26];
  const float* loc1_b  = (const float*)d_in[27];
  const float* loc2_w  = (const float*)d_in[28];
  const float* loc2_b  = (const float*)d_in[29];
  const float* bn0     = (const float*)d_in[30];
  const float* gcn1_bn = (const float*)d_in[31];
  const float* gcn2_bn = (const float*)d_in[32];
  const float* gcn3_bn = (const float*)d_in[33];
  const float* loc1_bn = (const float*)d_in[34];
  const float* loc2_bn = (const float*)d_in[35];
  float* out = (float*)d_out;
  (void)in_sizes; (void)n_in; (void)out_size; (void)ws_size;

  char* ws = (char*)d_ws;
  size_t off = 0;
  auto take = [&](size_t bytes) -> char* {
    char* p = ws + off;
    off += (bytes + 255) & ~(size_t)255;
    return p;
  };
  const size_t M  = 200704;  // 4*224*224 total positions
  const size_t Mc = 50176;   // 224*224 per batch chunk (S=1: L3-friendly)
  float* tem1 = (float*)take(256 * 224 * 4);
  float* spa1 = (float*)take(64 * 224 * 4);
  bf16* WmH   = (bf16*)take(128 * 128 * 2);
  bf16* WmL   = (bf16*)take(128 * 128 * 2);
  float* dvec = (float*)take(128 * 4);
  bf16* wb    = (bf16*)take(458752 * 2);  // gcn weights hi/lo packed
  float* Hm   = (float*)take(4 * 20 * 256 * 4);
  float* Z1   = (float*)take(4 * 20 * 256 * 4);
  float* Hred = (float*)take(896 * 256 * 4);
  bf16* H0 = (bf16*)take(M * 128 * 2);    // full H0 [M,128]
  bf16* YZ = (bf16*)take(Mc * 256 * 2);   // Y half / Z half; Y3 spans both
  bf16* Wb = (bf16*)take(Mc * 256 * 2);   // H2 row-major
  bf16* HtV = (bf16*)take(Mc * 256 * 2);  // Ht (H0t/H1t/H2t) then H3 (conv3 out)
  bf16* Gm = (bf16*)take(Mc * 224 * 2);   // softmax probs per chunk
  bf16* Yr = YZ;
  bf16* Zr = YZ + Mc * 128;

  bf16* g1w_h  = wb;           bf16* g1w_l  = wb + 16384;
  bf16* g1w1_h = wb + 32768;   bf16* g1w1_l = wb + 49152;
  bf16* g2w_h  = wb + 65536;   bf16* g2w_l  = wb + 98304;
  bf16* g2w1_h = wb + 131072;  bf16* g2w1_l = wb + 163840;
  bf16* g3w_h  = wb + 196608;  bf16* g3w_l  = wb + 262144;
  bf16* g3w1_h = wb + 327680;  bf16* g3w1_l = wb + 393216;

  hipMemsetAsync(Hred, 0, 896 * 256 * 4, stream);
  k_small<<<280, 256, 0, stream>>>(te1_w, te1_b, te2_w, te2_b,
                                   se1_w, se1_b, se2_w, se2_b, tem1, spa1);
  k_wm<<<64, 256, 0, stream>>>(g1_w, g2_w, g1_b, WmH, WmL, dvec);
  k_wcvt<<<896, 256, 0, stream>>>(gcn1_w, gcn1_w1, gcn2_w, gcn2_w1, gcn3_w, gcn3_w1, wb);
  k_h0<<<896, 256, 0, stream>>>(x, bn0, je1_w, je1_b, je2_w, je2_b, spa1, H0);

  for (int b = 0; b < 4; ++b) {
    const bf16* H0c = H0 + (size_t)b * Mc * 128;
    // A = H0c @ Wm^T + dvec  (fused q/k)
    k_conv_mfma<128, 128, 0, 0><<<dim3(784, 1), 256, 0, stream>>>(
        H0c, WmH, WmL, nullptr, nullptr, nullptr, dvec, nullptr, 0, Yr, nullptr);
    // H0t for apply1
    k_transpose128<<<dim3(7, 4, 224), 256, 0, stream>>>(H0c, HtV);
    // scores + softmax
    k_scores_mfma<<<dim3(4, 224), 256, 0, stream>>>(Yr, H0c, Gm);
    // gcn1
    k_apply_mfma<128><<<dim3(7, 224), 256, 0, stream>>>(Gm, HtV, Yr);
    k_conv_mfma<128, 128, 1, 1><<<dim3(784, 1), 256, 0, stream>>>(
        Yr, g1w_h, g1w_l, H0c, g1w1_h, g1w1_l, gcn1_b, gcn1_bn, 1, Zr, HtV);
    // gcn2
    k_apply_mfma<128><<<dim3(7, 224), 256, 0, stream>>>(Gm, HtV, Yr);
    k_conv_mfma<128, 256, 1, 1><<<dim3(784, 2), 256, 0, stream>>>(
        Yr, g2w_h, g2w_l, Zr, g2w1_h, g2w1_l, gcn2_b, gcn2_bn, 1, Wb, HtV);
    // gcn3
    k_apply_mfma<256><<<dim3(7, 224), 256, 0, stream>>>(Gm, HtV, YZ);
    k_conv_mfma<256, 256, 1, 0><<<dim3(784, 2), 256, 0, stream>>>(
        YZ, g3w_h, g3w_l, Wb, g3w1_h, g3w1_l, gcn3_b, gcn3_bn, 1, HtV, nullptr);
    // partial max over j into Hred (atomicMax, values >= 0)
    k_reduce<<<dim3(224, 7), 256, 0, stream>>>(HtV, Hred, b * 224);
  }
  k_head_a<<<dim3(4, 20), 256, 0, stream>>>(Hred, tem1, Hm);
  k_head_b<<<dim3(4, 20), 256, 0, stream>>>(Hm, loc1_w, loc1_b, loc1_bn, Z1);
  k_head_c<<<4, 512, 0, stream>>>(Z1, loc2_w, loc2_b, loc2_bn, out);
}

// Round 6
// 1488.226 us; speedup vs baseline: 1.2814x; 1.1524x over previous
//
#include <hip/hip_runtime.h>
#include <hip/hip_bf16.h>

typedef __hip_bfloat16 bf16;
typedef __attribute__((ext_vector_type(8))) short v8s;
typedef __attribute__((ext_vector_type(4))) float f32x4;
#define EPS 1e-5f
#define MFMA16(a, b, c) __builtin_amdgcn_mfma_f32_16x16x32_bf16(a, b, c, 0, 0, 0)

__device__ __forceinline__ float bfu(unsigned int s) {
  union { unsigned int u; float f; } c; c.u = s << 16; return c.f;
}
__device__ __forceinline__ bf16 f2b(float v) { return __float2bfloat16(v); }

// ---------------------------------------------------------------------------
// K0: tem1 (256x224) and spa1 (64x224) closed-form tables
// ---------------------------------------------------------------------------
__global__ __launch_bounds__(256) void k_small(
    const float* __restrict__ te1_w, const float* __restrict__ te1_b,
    const float* __restrict__ te2_w, const float* __restrict__ te2_b,
    const float* __restrict__ se1_w, const float* __restrict__ se1_b,
    const float* __restrict__ se2_w, const float* __restrict__ se2_b,
    float* __restrict__ tem1, float* __restrict__ spa1) {
  int idx = blockIdx.x * 256 + threadIdx.x;
  if (idx >= (256 + 64) * 224) return;
  int o = idx / 224, t = idx % 224;
  if (o < 256) {
    float acc = te2_b[o];
    for (int c = 0; c < 64; ++c) {
      float u = fmaxf(te1_w[c * 224 + t] + te1_b[c], 0.f);
      acc += te2_w[o * 64 + c] * u;
    }
    tem1[o * 224 + t] = fmaxf(acc, 0.f);
  } else {
    int oo = o - 256;
    float acc = se2_b[oo];
    for (int c = 0; c < 64; ++c) {
      float u = fmaxf(se1_w[c * 224 + t] + se1_b[c], 0.f);
      acc += se2_w[oo * 64 + c] * u;
    }
    spa1[oo * 224 + t] = fmaxf(acc, 0.f);
  }
}

// ---------------------------------------------------------------------------
// K0b: Wm = g1^T g2 fused attention matrix (bf16 hi/lo), dvec = g2^T b1
// ---------------------------------------------------------------------------
__global__ __launch_bounds__(256) void k_wm(
    const float* __restrict__ g1_w, const float* __restrict__ g2_w,
    const float* __restrict__ g1_b, bf16* __restrict__ WmH, bf16* __restrict__ WmL,
    float* __restrict__ dvec) {
  int idx = blockIdx.x * 256 + threadIdx.x;
  if (idx >= 128 * 128) return;
  int o = idx >> 7, c = idx & 127;
  float acc = 0.f;
  for (int t = 0; t < 256; ++t) acc += g1_w[t * 128 + c] * g2_w[t * 128 + o];
  bf16 hi = f2b(acc);
  WmH[o * 128 + c] = hi;
  WmL[o * 128 + c] = f2b(acc - __bfloat162float(hi));
  if (c == 0) {
    float d = 0.f;
    for (int t = 0; t < 256; ++t) d += g2_w[t * 128 + o] * g1_b[t];
    dvec[o] = d;
  }
}

// ---------------------------------------------------------------------------
// K0c: convert the 6 gcn weights to bf16 hi/lo pairs (packed buffer)
// ---------------------------------------------------------------------------
__global__ __launch_bounds__(256) void k_wcvt(
    const float* __restrict__ g1w, const float* __restrict__ g1w1,
    const float* __restrict__ g2w, const float* __restrict__ g2w1,
    const float* __restrict__ g3w, const float* __restrict__ g3w1,
    bf16* __restrict__ dst) {
  int idx = blockIdx.x * 256 + threadIdx.x;
  const float* src; size_t base; int off; int sz;
  if (idx < 16384)        { src = g1w;  base = 0;      off = idx;          sz = 16384; }
  else if (idx < 32768)   { src = g1w1; base = 32768;  off = idx - 16384;  sz = 16384; }
  else if (idx < 65536)   { src = g2w;  base = 65536;  off = idx - 32768;  sz = 32768; }
  else if (idx < 98304)   { src = g2w1; base = 131072; off = idx - 65536;  sz = 32768; }
  else if (idx < 163840)  { src = g3w;  base = 196608; off = idx - 98304;  sz = 65536; }
  else if (idx < 229376)  { src = g3w1; base = 327680; off = idx - 163840; sz = 65536; }
  else return;
  float v = src[off];
  bf16 hi = f2b(v);
  dst[base + off] = hi;
  dst[base + sz + off] = f2b(v - __bfloat162float(hi));
}

// ---------------------------------------------------------------------------
// K1: bn0 + je1 + relu + je2 + relu -> H0[b,t,j,c]
// ---------------------------------------------------------------------------
__global__ __launch_bounds__(256) void k_h0(
    const float* __restrict__ x, const float* __restrict__ bn0,
    const float* __restrict__ je1_w, const float* __restrict__ je1_b,
    const float* __restrict__ je2_w, const float* __restrict__ je2_b,
    const float* __restrict__ spa1, bf16* __restrict__ H0) {
  int bj = blockIdx.x;
  int b = bj / 224, j = bj % 224;
  __shared__ float w1s[192], b1s[64], w2s[4096], b2s[64];
  int tid = threadIdx.x;
  for (int i = tid; i < 192; i += 256) w1s[i] = je1_w[i];
  for (int i = tid; i < 64; i += 256) { b1s[i] = je1_b[i]; b2s[i] = je2_b[i]; }
  for (int i = tid; i < 4096; i += 256) w2s[i] = je2_w[i];
  __syncthreads();
  int t = tid;
  if (t >= 224) return;
  float xf[3];
  #pragma unroll
  for (int c = 0; c < 3; ++c) {
    int ch = c * 224 + j;
    float g = bn0[ch], bb = bn0[672 + ch], m = bn0[2 * 672 + ch], v = bn0[3 * 672 + ch];
    float inv = g * rsqrtf(v + EPS);
    float xv = x[((size_t)(b * 3 + c) * 224 + j) * 224 + t];
    xf[c] = (xv - m) * inv + bb;
  }
  float u[64];
  #pragma unroll
  for (int c = 0; c < 64; ++c) {
    float a = w1s[c * 3 + 0] * xf[0] + w1s[c * 3 + 1] * xf[1] + w1s[c * 3 + 2] * xf[2] + b1s[c];
    u[c] = fmaxf(a, 0.f);
  }
  size_t base = ((size_t)(b * 224 + t) * 224 + j) * 128;
  for (int o = 0; o < 64; ++o) {
    float acc = b2s[o];
    #pragma unroll
    for (int c = 0; c < 64; ++c) acc += w2s[o * 64 + c] * u[c];
    H0[base + o] = f2b(fmaxf(acc, 0.f));
  }
  for (int o = 0; o < 64; ++o) H0[base + 64 + o] = f2b(spa1[o * 224 + j]);
}

// ---------------------------------------------------------------------------
// K2: MFMA conv1x1, LDS-staged A with double buffer + register prefetch.
// Block 128(M)x128(N), 4 waves 2x2, wave tile 64x64 (4x4 MFMA grid), BK=64.
// A-tile LDS layout kpart-major [8][128][8elem] (bank-balanced, 16B aligned).
// Weights (bf16 hi/lo) loaded direct from global (L2-hot).
// Optional transposed output out_t[(bt*Cout + c)*224 + j].
// ---------------------------------------------------------------------------
template <int CIN, int COUT, int DUAL, int WRITE_T>
__global__ __launch_bounds__(256, 2) void k_conv_mfma(
    const bf16* __restrict__ in1,
    const bf16* __restrict__ w1h, const bf16* __restrict__ w1l,
    const bf16* __restrict__ in2,
    const bf16* __restrict__ w2h, const bf16* __restrict__ w2l,
    const float* __restrict__ bias, const float* __restrict__ bn,
    int do_relu, bf16* __restrict__ out, bf16* __restrict__ out_t) {
  constexpr int BK = 64;
  constexpr int NST = CIN / BK;                 // K-steps
  constexpr int TSZ = 8 * 128 * 8;              // 8192 elems = 16KB per matrix
  __shared__ bf16 smem[2 * (DUAL + 1) * TSZ];
  const int tid = threadIdx.x;
  const int w = tid >> 6, lane = tid & 63;
  const int l15 = lane & 15, q = lane >> 4;
  const int mh = w >> 1, nh = w & 1;
  const int m0 = blockIdx.x * 128;
  const int n0 = blockIdx.y * 128 + nh * 64;

  f32x4 acc[4][4] = {};  // [i][ns]
  v8s T1[4], T2[4];

  auto gload = [&](int k0) {
    #pragma unroll
    for (int sh = 0; sh < 4; ++sh) {
      int c = sh * 256 + tid;
      int r = c >> 3, kp = c & 7;
      T1[sh] = *(const v8s*)(in1 + (size_t)(m0 + r) * CIN + k0 + kp * 8);
      if (DUAL) T2[sh] = *(const v8s*)(in2 + (size_t)(m0 + r) * CIN + k0 + kp * 8);
    }
  };
  auto swrite = [&](int buf) {
    bf16* base = smem + buf * (DUAL + 1) * TSZ;
    #pragma unroll
    for (int sh = 0; sh < 4; ++sh) {
      int c = sh * 256 + tid;
      int r = c >> 3, kp = c & 7;
      *(v8s*)(base + (kp * 128 + r) * 8) = T1[sh];
      if (DUAL) *(v8s*)(base + TSZ + (kp * 128 + r) * 8) = T2[sh];
    }
  };

  gload(0);
  swrite(0);
  for (int s = 0; s < NST; ++s) {
    if (s + 1 < NST) gload((s + 1) * BK);
    __syncthreads();
    const bf16* base = smem + (s & 1) * (DUAL + 1) * TSZ;
    #pragma unroll
    for (int sub = 0; sub < 2; ++sub) {
      const int kg = s * BK + sub * 32 + q * 8;  // global k offset for this lane
      const int kp = sub * 4 + q;                 // tile kpart
      v8s a1[4], a2[4];
      #pragma unroll
      for (int i = 0; i < 4; ++i) {
        int row = mh * 64 + i * 16 + l15;
        a1[i] = *(const v8s*)(base + (kp * 128 + row) * 8);
        if (DUAL) a2[i] = *(const v8s*)(base + TSZ + (kp * 128 + row) * 8);
      }
      #pragma unroll
      for (int ns = 0; ns < 4; ++ns) {
        const size_t wrow = (size_t)(n0 + ns * 16 + l15) * CIN + kg;
        v8s bh = *(const v8s*)(w1h + wrow);
        v8s bl = *(const v8s*)(w1l + wrow);
        #pragma unroll
        for (int i = 0; i < 4; ++i) {
          acc[i][ns] = MFMA16(a1[i], bl, acc[i][ns]);
          acc[i][ns] = MFMA16(a1[i], bh, acc[i][ns]);
        }
        if (DUAL) {
          v8s ch = *(const v8s*)(w2h + wrow);
          v8s cl = *(const v8s*)(w2l + wrow);
          #pragma unroll
          for (int i = 0; i < 4; ++i) {
            acc[i][ns] = MFMA16(a2[i], cl, acc[i][ns]);
            acc[i][ns] = MFMA16(a2[i], ch, acc[i][ns]);
          }
        }
      }
    }
    if (s + 1 < NST) swrite((s + 1) & 1);
  }
  #pragma unroll
  for (int ns = 0; ns < 4; ++ns) {
    const int oc = n0 + ns * 16 + l15;
    float sc = 1.f, sh = bias[oc];
    if (bn != nullptr) {
      float g = bn[oc], bb = bn[COUT + oc], m = bn[2 * COUT + oc], v = bn[3 * COUT + oc];
      sc = g * rsqrtf(v + EPS);
      sh = (sh - m) * sc + bb;
    }
    #pragma unroll
    for (int i = 0; i < 4; ++i) {
      const int mbase = m0 + mh * 64 + i * 16 + q * 4;
      float vals[4];
      #pragma unroll
      for (int r = 0; r < 4; ++r) {
        float val = acc[i][ns][r] * sc + sh;
        if (do_relu) val = fmaxf(val, 0.f);
        vals[r] = val;
        out[(size_t)(mbase + r) * COUT + oc] = f2b(val);
      }
      if (WRITE_T) {
        const int bt = mbase / 224;  // 4-row store group stays in one bt (224%4==0)
        const int j = mbase - bt * 224;
        unsigned short s0 = __bfloat16_as_ushort(f2b(vals[0]));
        unsigned short s1 = __bfloat16_as_ushort(f2b(vals[1]));
        unsigned short s2 = __bfloat16_as_ushort(f2b(vals[2]));
        unsigned short s3 = __bfloat16_as_ushort(f2b(vals[3]));
        uint2 pk;
        pk.x = (unsigned int)s0 | ((unsigned int)s1 << 16);
        pk.y = (unsigned int)s2 | ((unsigned int)s3 << 16);
        *(uint2*)((unsigned short*)out_t + ((size_t)bt * COUT + oc) * 224 + j) = pk;
      }
    }
  }
}

// ---------------------------------------------------------------------------
// K2b: per-chunk transpose of H0c [bt*224+j][128] -> Ht [(bt*128)+c][224]
// ---------------------------------------------------------------------------
__global__ __launch_bounds__(256) void k_transpose128(
    const bf16* __restrict__ src, bf16* __restrict__ dst) {
  const int j0 = blockIdx.x * 32, c0 = blockIdx.y * 32, bt = blockIdx.z;
  __shared__ unsigned short ts[32][33];
  const int tid = threadIdx.x;
  {
    int r = tid >> 3, cg = (tid & 7) * 4;
    const unsigned short* sp =
        (const unsigned short*)src + ((size_t)(bt * 224) + j0 + r) * 128 + c0 + cg;
    uint2 u = *(const uint2*)sp;
    ts[r][cg + 0] = (unsigned short)(u.x & 0xffffu);
    ts[r][cg + 1] = (unsigned short)(u.x >> 16);
    ts[r][cg + 2] = (unsigned short)(u.y & 0xffffu);
    ts[r][cg + 3] = (unsigned short)(u.y >> 16);
  }
  __syncthreads();
  {
    int c = tid >> 3, jg = (tid & 7) * 4;
    uint2 o;
    o.x = (unsigned int)ts[jg + 0][c] | ((unsigned int)ts[jg + 1][c] << 16);
    o.y = (unsigned int)ts[jg + 2][c] | ((unsigned int)ts[jg + 3][c] << 16);
    *(uint2*)((unsigned short*)dst + ((size_t)(bt * 128) + c0 + c) * 224 + j0 + jg) = o;
  }
}

// ---------------------------------------------------------------------------
// K3: MFMA scores + softmax. A[bt*224+j][128], H[bt*224+k][128] ->
// G[bt][j][k] = softmax_k(A_j . H_k). Wave = 16 j-rows x all 224 k.
// ---------------------------------------------------------------------------
__global__ __launch_bounds__(256, 3) void k_scores_mfma(
    const bf16* __restrict__ A, const bf16* __restrict__ H, bf16* __restrict__ G) {
  const int bt = blockIdx.y;
  const int w = threadIdx.x >> 6, lane = threadIdx.x & 63;
  const int mt = blockIdx.x * 4 + w;
  if (mt >= 14) return;
  const int l15 = lane & 15, q = lane >> 4;
  const int j0 = mt * 16;
  const bf16* Ab = A + (size_t)bt * 224 * 128;
  const bf16* Hb = H + (size_t)bt * 224 * 128;
  v8s a[4];
  #pragma unroll
  for (int ks = 0; ks < 4; ++ks)
    a[ks] = *(const v8s*)(Ab + (size_t)(j0 + l15) * 128 + ks * 32 + q * 8);
  f32x4 s[14];
  #pragma unroll
  for (int nt = 0; nt < 14; ++nt) {
    f32x4 acc = {0.f, 0.f, 0.f, 0.f};
    #pragma unroll
    for (int ks = 0; ks < 4; ++ks) {
      v8s b = *(const v8s*)(Hb + (size_t)(nt * 16 + l15) * 128 + ks * 32 + q * 8);
      acc = MFMA16(a[ks], b, acc);
    }
    s[nt] = acc;
  }
  bf16* Gb = G + ((size_t)bt * 224 + j0) * 224;
  #pragma unroll
  for (int r = 0; r < 4; ++r) {
    float mx = -1e30f;
    #pragma unroll
    for (int nt = 0; nt < 14; ++nt) mx = fmaxf(mx, s[nt][r]);
    mx = fmaxf(mx, __shfl_xor(mx, 1));
    mx = fmaxf(mx, __shfl_xor(mx, 2));
    mx = fmaxf(mx, __shfl_xor(mx, 4));
    mx = fmaxf(mx, __shfl_xor(mx, 8));
    float sum = 0.f;
    #pragma unroll
    for (int nt = 0; nt < 14; ++nt) {
      float e = __expf(s[nt][r] - mx);
      s[nt][r] = e;
      sum += e;
    }
    sum += __shfl_xor(sum, 1);
    sum += __shfl_xor(sum, 2);
    sum += __shfl_xor(sum, 4);
    sum += __shfl_xor(sum, 8);
    const float inv = 1.f / sum;
    const int jr = q * 4 + r;
    #pragma unroll
    for (int nt = 0; nt < 14; ++nt)
      Gb[(size_t)jr * 224 + nt * 16 + l15] = f2b(s[nt][r] * inv);
  }
}

// ---------------------------------------------------------------------------
// K4: MFMA apply: Y[bt*224+j][c] = sum_k G[bt][j][k]*Ht[bt][c][k]
// Grid (7, bt). Block = 4 waves sharing the same 32 j-rows, C split 4 ways.
// ---------------------------------------------------------------------------
template <int C>
__global__ __launch_bounds__(256, 3) void k_apply_mfma(
    const bf16* __restrict__ G, const bf16* __restrict__ Ht,
    bf16* __restrict__ Y) {
  const int bt = blockIdx.y;
  const int w = threadIdx.x >> 6;
  const int lane = threadIdx.x & 63;
  const int l15 = lane & 15, q = lane >> 4;
  const int j0 = blockIdx.x * 32;
  const bf16* Gb = G + (size_t)bt * 224 * 224;
  const bf16* Hb = Ht + (size_t)bt * C * 224;
  bf16* Yb = Y + (size_t)bt * 224 * C;
  v8s a[2][7];
  #pragma unroll
  for (int h = 0; h < 2; ++h)
    #pragma unroll
    for (int ks = 0; ks < 7; ++ks)
      a[h][ks] = *(const v8s*)(Gb + (size_t)(j0 + h * 16 + l15) * 224 + ks * 32 + q * 8);
  constexpr int NPW = C / 64;  // nt per wave
  #pragma unroll
  for (int u = 0; u < NPW; ++u) {
    const int nt = w * NPW + u;
    f32x4 acc0 = {0.f, 0.f, 0.f, 0.f};
    f32x4 acc1 = {0.f, 0.f, 0.f, 0.f};
    #pragma unroll
    for (int ks = 0; ks < 7; ++ks) {
      v8s b = *(const v8s*)(Hb + (size_t)(nt * 16 + l15) * 224 + ks * 32 + q * 8);
      acc0 = MFMA16(a[0][ks], b, acc0);
      acc1 = MFMA16(a[1][ks], b, acc1);
    }
    const int c = nt * 16 + l15;
    #pragma unroll
    for (int r = 0; r < 4; ++r) {
      Yb[(size_t)(j0 + q * 4 + r) * C + c] = f2b(acc0[r]);
      Yb[(size_t)(j0 + 16 + q * 4 + r) * C + c] = f2b(acc1[r]);
    }
  }
}

// ---------------------------------------------------------------------------
// K5: partial max over j (32 rows per block) -> atomicMax into Hred (>=0)
// ---------------------------------------------------------------------------
__global__ __launch_bounds__(256) void k_reduce(
    const bf16* __restrict__ H3, float* __restrict__ Hred, int row0) {
  int t = blockIdx.x;
  int jb = blockIdx.y;
  int o = threadIdx.x;
  const unsigned short* p =
      (const unsigned short*)(H3 + ((size_t)t * 224 + jb * 32) * 256 + o);
  float mx = 0.f;
  #pragma unroll 8
  for (int j = 0; j < 32; ++j) mx = fmaxf(mx, bfu(p[(size_t)j * 256]));
  atomicMax((unsigned int*)&Hred[(size_t)(row0 + t) * 256 + o], __float_as_uint(mx));
}

// ---------------------------------------------------------------------------
// K6a: adaptive max pool 224 -> 20 over t, adding tem1[c,t]. Grid (4,20).
// ---------------------------------------------------------------------------
__global__ __launch_bounds__(256) void k_head_a(
    const float* __restrict__ Hred, const float* __restrict__ tem1,
    float* __restrict__ Hm) {
  int b = blockIdx.x, i = blockIdx.y, c = threadIdx.x;
  int s = (i * 224) / 20, e = ((i + 1) * 224 + 19) / 20;
  float mx = -1e30f;
  for (int t = s; t < e; ++t)
    mx = fmaxf(mx, Hred[((size_t)b * 224 + t) * 256 + c] + tem1[c * 224 + t]);
  Hm[((size_t)b * 20 + i) * 256 + c] = mx;
}

// ---------------------------------------------------------------------------
// K6b: loc1 width-3 conv + bn + relu. Grid (4,20), block 256 (o).
// ---------------------------------------------------------------------------
__global__ __launch_bounds__(256) void k_head_b(
    const float* __restrict__ Hm, const float* __restrict__ loc1_w,
    const float* __restrict__ loc1_b, const float* __restrict__ loc1_bn,
    float* __restrict__ Z1) {
  int b = blockIdx.x, r = blockIdx.y;
  __shared__ float hs[3 * 256];
  int tid = threadIdx.x;
  for (int idx = tid; idx < 768; idx += 256) {
    int dx = idx >> 8, c = idx & 255;
    int u = r + dx - 1;
    hs[idx] = (u >= 0 && u < 20) ? Hm[((size_t)b * 20 + u) * 256 + c] : 0.f;
  }
  __syncthreads();
  int o = tid;
  float acc = loc1_b[o];
  const float* wp = loc1_w + (size_t)o * 768;
  #pragma unroll 4
  for (int c = 0; c < 256; ++c) {
    acc += wp[c * 3 + 0] * hs[c] + wp[c * 3 + 1] * hs[256 + c] + wp[c * 3 + 2] * hs[512 + c];
  }
  float g = loc1_bn[o], bb = loc1_bn[256 + o], m = loc1_bn[512 + o], v = loc1_bn[768 + o];
  float sc = g * rsqrtf(v + EPS);
  Z1[((size_t)b * 20 + r) * 256 + o] = fmaxf((acc - m) * sc + bb, 0.f);
}

// ---------------------------------------------------------------------------
// K6c: loc2 + bn + relu + max over 20 positions. Grid 4, block 512 (o2).
// ---------------------------------------------------------------------------
__global__ __launch_bounds__(512) void k_head_c(
    const float* __restrict__ Z1, const float* __restrict__ loc2_w,
    const float* __restrict__ loc2_b, const float* __restrict__ loc2_bn,
    float* __restrict__ out) {
  int b = blockIdx.x;
  int tid = threadIdx.x;
  __shared__ float zs[20 * 256];
  for (int idx = tid; idx < 5120; idx += 512) zs[idx] = Z1[(size_t)b * 5120 + idx];
  __syncthreads();
  int o2 = tid;
  float acc[20];
  float bi = loc2_b[o2];
  #pragma unroll
  for (int r = 0; r < 20; ++r) acc[r] = bi;
  const float* wp = loc2_w + (size_t)o2 * 256;
  for (int c = 0; c < 256; ++c) {
    float wv = wp[c];
    #pragma unroll
    for (int r = 0; r < 20; ++r) acc[r] += wv * zs[r * 256 + c];
  }
  float g = loc2_bn[o2], bb = loc2_bn[512 + o2], m = loc2_bn[1024 + o2], v = loc2_bn[1536 + o2];
  float sc = g * rsqrtf(v + EPS);
  float best = -1e30f;
  #pragma unroll
  for (int r = 0; r < 20; ++r) best = fmaxf(best, fmaxf((acc[r] - m) * sc + bb, 0.f));
  out[(size_t)b * 512 + o2] = best;
}

// ---------------------------------------------------------------------------
extern "C" void kernel_launch(void* const* d_in, const int* in_sizes, int n_in,
                              void* d_out, int out_size, void* d_ws, size_t ws_size,
                              hipStream_t stream) {
  const float* x       = (const float*)d_in[0];
  const float* je1_w   = (const float*)d_in[1];
  const float* je1_b   = (const float*)d_in[2];
  const float* je2_w   = (const float*)d_in[3];
  const float* je2_b   = (const float*)d_in[4];
  const float* se1_w   = (const float*)d_in[5];
  const float* se1_b   = (const float*)d_in[6];
  const float* se2_w   = (const float*)d_in[7];
  const float* se2_b   = (const float*)d_in[8];
  const float* te1_w   = (const float*)d_in[9];
  const float* te1_b   = (const float*)d_in[10];
  const float* te2_w   = (const float*)d_in[11];
  const float* te2_b   = (const float*)d_in[12];
  const float* g1_w    = (const float*)d_in[13];
  const float* g1_b    = (const float*)d_in[14];
  const float* g2_w    = (const float*)d_in[15];
  const float* gcn1_w  = (const float*)d_in[17];
  const float* gcn1_w1 = (const float*)d_in[18];
  const float* gcn1_b  = (const float*)d_in[19];
  const float* gcn2_w  = (const float*)d_in[20];
  const float* gcn2_w1 = (const float*)d_in[21];
  const float* gcn2_b  = (const float*)d_in[22];
  const float* gcn3_w  = (const float*)d_in[23];
  const float* gcn3_w1 = (const float*)d_in[24];
  const float* gcn3_b  = (const float*)d_in[25];
  const float* loc1_w  = (const float*)d_in[26];
  const float* loc1_b  = (const float*)d_in[27];
  const float* loc2_w  = (const float*)d_in[28];
  const float* loc2_b  = (const float*)d_in[29];
  const float* bn0     = (const float*)d_in[30];
  const float* gcn1_bn = (const float*)d_in[31];
  const float* gcn2_bn = (const float*)d_in[32];
  const float* gcn3_bn = (const float*)d_in[33];
  const float* loc1_bn = (const float*)d_in[34];
  const float* loc2_bn = (const float*)d_in[35];
  float* out = (float*)d_out;
  (void)in_sizes; (void)n_in; (void)out_size; (void)ws_size;

  char* ws = (char*)d_ws;
  size_t off = 0;
  auto take = [&](size_t bytes) -> char* {
    char* p = ws + off;
    off += (bytes + 255) & ~(size_t)255;
    return p;
  };
  const size_t M  = 200704;  // 4*224*224 total positions
  const size_t Mc = 50176;   // 224*224 per batch chunk (S=1: L3-friendly)
  float* tem1 = (float*)take(256 * 224 * 4);
  float* spa1 = (float*)take(64 * 224 * 4);
  bf16* WmH   = (bf16*)take(128 * 128 * 2);
  bf16* WmL   = (bf16*)take(128 * 128 * 2);
  float* dvec = (float*)take(128 * 4);
  bf16* wb    = (bf16*)take(458752 * 2);  // gcn weights hi/lo packed
  float* Hm   = (float*)take(4 * 20 * 256 * 4);
  float* Z1   = (float*)take(4 * 20 * 256 * 4);
  float* Hred = (float*)take(896 * 256 * 4);
  bf16* H0 = (bf16*)take(M * 128 * 2);    // full H0 [M,128]
  bf16* YZ = (bf16*)take(Mc * 256 * 2);   // Y half / Z half; Y3 spans both
  bf16* Wb = (bf16*)take(Mc * 256 * 2);   // H2 row-major
  bf16* HtV = (bf16*)take(Mc * 256 * 2);  // Ht (H0t/H1t/H2t) then H3 (conv3 out)
  bf16* Gm = (bf16*)take(Mc * 224 * 2);   // softmax probs per chunk
  bf16* Yr = YZ;
  bf16* Zr = YZ + Mc * 128;

  bf16* g1w_h  = wb;           bf16* g1w_l  = wb + 16384;
  bf16* g1w1_h = wb + 32768;   bf16* g1w1_l = wb + 49152;
  bf16* g2w_h  = wb + 65536;   bf16* g2w_l  = wb + 98304;
  bf16* g2w1_h = wb + 131072;  bf16* g2w1_l = wb + 163840;
  bf16* g3w_h  = wb + 196608;  bf16* g3w_l  = wb + 262144;
  bf16* g3w1_h = wb + 327680;  bf16* g3w1_l = wb + 393216;

  hipMemsetAsync(Hred, 0, 896 * 256 * 4, stream);
  k_small<<<280, 256, 0, stream>>>(te1_w, te1_b, te2_w, te2_b,
                                   se1_w, se1_b, se2_w, se2_b, tem1, spa1);
  k_wm<<<64, 256, 0, stream>>>(g1_w, g2_w, g1_b, WmH, WmL, dvec);
  k_wcvt<<<896, 256, 0, stream>>>(gcn1_w, gcn1_w1, gcn2_w, gcn2_w1, gcn3_w, gcn3_w1, wb);
  k_h0<<<896, 256, 0, stream>>>(x, bn0, je1_w, je1_b, je2_w, je2_b, spa1, H0);

  for (int b = 0; b < 4; ++b) {
    const bf16* H0c = H0 + (size_t)b * Mc * 128;
    // A = H0c @ Wm^T + dvec  (fused q/k)
    k_conv_mfma<128, 128, 0, 0><<<dim3(392, 1), 256, 0, stream>>>(
        H0c, WmH, WmL, nullptr, nullptr, nullptr, dvec, nullptr, 0, Yr, nullptr);
    // H0t for apply1
    k_transpose128<<<dim3(7, 4, 224), 256, 0, stream>>>(H0c, HtV);
    // scores + softmax
    k_scores_mfma<<<dim3(4, 224), 256, 0, stream>>>(Yr, H0c, Gm);
    // gcn1
    k_apply_mfma<128><<<dim3(7, 224), 256, 0, stream>>>(Gm, HtV, Yr);
    k_conv_mfma<128, 128, 1, 1><<<dim3(392, 1), 256, 0, stream>>>(
        Yr, g1w_h, g1w_l, H0c, g1w1_h, g1w1_l, gcn1_b, gcn1_bn, 1, Zr, HtV);
    // gcn2
    k_apply_mfma<128><<<dim3(7, 224), 256, 0, stream>>>(Gm, HtV, Yr);
    k_conv_mfma<128, 256, 1, 1><<<dim3(392, 2), 256, 0, stream>>>(
        Yr, g2w_h, g2w_l, Zr, g2w1_h, g2w1_l, gcn2_b, gcn2_bn, 1, Wb, HtV);
    // gcn3
    k_apply_mfma<256><<<dim3(7, 224), 256, 0, stream>>>(Gm, HtV, YZ);
    k_conv_mfma<256, 256, 1, 0><<<dim3(392, 2), 256, 0, stream>>>(
        YZ, g3w_h, g3w_l, Wb, g3w1_h, g3w1_l, gcn3_b, gcn3_bn, 1, HtV, nullptr);
    // partial max over j into Hred (atomicMax, values >= 0)
    k_reduce<<<dim3(224, 7), 256, 0, stream>>>(HtV, Hred, b * 224);
  }
  k_head_a<<<dim3(4, 20), 256, 0, stream>>>(Hred, tem1, Hm);
  k_head_b<<<dim3(4, 20), 256, 0, stream>>>(Hm, loc1_w, loc1_b, loc1_bn, Z1);
  k_head_c<<<4, 512, 0, stream>>>(Z1, loc2_w, loc2_b, loc2_bn, out);
}

// Round 7
// 1484.017 us; speedup vs baseline: 1.2850x; 1.0028x over previous
//
#include <hip/hip_runtime.h>
#include <hip/hip_bf16.h>

typedef __hip_bfloat16 bf16;
typedef __attribute__((ext_vector_type(8))) short v8s;
typedef __attribute__((ext_vector_type(4))) float f32x4;
#define EPS 1e-5f
#define MFMA16(a, b, c) __builtin_amdgcn_mfma_f32_16x16x32_bf16(a, b, c, 0, 0, 0)

__device__ __forceinline__ float bfu(unsigned int s) {
  union { unsigned int u; float f; } c; c.u = s << 16; return c.f;
}
__device__ __forceinline__ bf16 f2b(float v) { return __float2bfloat16(v); }

// async 16B global -> LDS DMA (lane i lands at lds + i*16B)
__device__ __forceinline__ void gl_lds16(const bf16* g, bf16* l) {
  __builtin_amdgcn_global_load_lds(
      (const __attribute__((address_space(1))) void*)g,
      (__attribute__((address_space(3))) void*)l, 16, 0, 0);
}

// ---------------------------------------------------------------------------
// K0: tem1 (256x224) and spa1 (64x224) closed-form tables
// ---------------------------------------------------------------------------
__global__ __launch_bounds__(256) void k_small(
    const float* __restrict__ te1_w, const float* __restrict__ te1_b,
    const float* __restrict__ te2_w, const float* __restrict__ te2_b,
    const float* __restrict__ se1_w, const float* __restrict__ se1_b,
    const float* __restrict__ se2_w, const float* __restrict__ se2_b,
    float* __restrict__ tem1, float* __restrict__ spa1) {
  int idx = blockIdx.x * 256 + threadIdx.x;
  if (idx >= (256 + 64) * 224) return;
  int o = idx / 224, t = idx % 224;
  if (o < 256) {
    float acc = te2_b[o];
    for (int c = 0; c < 64; ++c) {
      float u = fmaxf(te1_w[c * 224 + t] + te1_b[c], 0.f);
      acc += te2_w[o * 64 + c] * u;
    }
    tem1[o * 224 + t] = fmaxf(acc, 0.f);
  } else {
    int oo = o - 256;
    float acc = se2_b[oo];
    for (int c = 0; c < 64; ++c) {
      float u = fmaxf(se1_w[c * 224 + t] + se1_b[c], 0.f);
      acc += se2_w[oo * 64 + c] * u;
    }
    spa1[oo * 224 + t] = fmaxf(acc, 0.f);
  }
}

// ---------------------------------------------------------------------------
// K0b: Wm = g1^T g2 fused attention matrix (bf16 hi/lo), dvec = g2^T b1
// ---------------------------------------------------------------------------
__global__ __launch_bounds__(256) void k_wm(
    const float* __restrict__ g1_w, const float* __restrict__ g2_w,
    const float* __restrict__ g1_b, bf16* __restrict__ WmH, bf16* __restrict__ WmL,
    float* __restrict__ dvec) {
  int idx = blockIdx.x * 256 + threadIdx.x;
  if (idx >= 128 * 128) return;
  int o = idx >> 7, c = idx & 127;
  float acc = 0.f;
  for (int t = 0; t < 256; ++t) acc += g1_w[t * 128 + c] * g2_w[t * 128 + o];
  bf16 hi = f2b(acc);
  WmH[o * 128 + c] = hi;
  WmL[o * 128 + c] = f2b(acc - __bfloat162float(hi));
  if (c == 0) {
    float d = 0.f;
    for (int t = 0; t < 256; ++t) d += g2_w[t * 128 + o] * g1_b[t];
    dvec[o] = d;
  }
}

// ---------------------------------------------------------------------------
// K0c: convert the 6 gcn weights to bf16 hi/lo pairs (packed buffer)
// ---------------------------------------------------------------------------
__global__ __launch_bounds__(256) void k_wcvt(
    const float* __restrict__ g1w, const float* __restrict__ g1w1,
    const float* __restrict__ g2w, const float* __restrict__ g2w1,
    const float* __restrict__ g3w, const float* __restrict__ g3w1,
    bf16* __restrict__ dst) {
  int idx = blockIdx.x * 256 + threadIdx.x;
  const float* src; size_t base; int off; int sz;
  if (idx < 16384)        { src = g1w;  base = 0;      off = idx;          sz = 16384; }
  else if (idx < 32768)   { src = g1w1; base = 32768;  off = idx - 16384;  sz = 16384; }
  else if (idx < 65536)   { src = g2w;  base = 65536;  off = idx - 32768;  sz = 32768; }
  else if (idx < 98304)   { src = g2w1; base = 131072; off = idx - 65536;  sz = 32768; }
  else if (idx < 163840)  { src = g3w;  base = 196608; off = idx - 98304;  sz = 65536; }
  else if (idx < 229376)  { src = g3w1; base = 327680; off = idx - 163840; sz = 65536; }
  else return;
  float v = src[off];
  bf16 hi = f2b(v);
  dst[base + off] = hi;
  dst[base + sz + off] = f2b(v - __bfloat162float(hi));
}

// ---------------------------------------------------------------------------
// K1: bn0 + je1 + relu + je2 + relu -> H0[b,t,j,c]
// ---------------------------------------------------------------------------
__global__ __launch_bounds__(256) void k_h0(
    const float* __restrict__ x, const float* __restrict__ bn0,
    const float* __restrict__ je1_w, const float* __restrict__ je1_b,
    const float* __restrict__ je2_w, const float* __restrict__ je2_b,
    const float* __restrict__ spa1, bf16* __restrict__ H0) {
  int bj = blockIdx.x;
  int b = bj / 224, j = bj % 224;
  __shared__ float w1s[192], b1s[64], w2s[4096], b2s[64];
  int tid = threadIdx.x;
  for (int i = tid; i < 192; i += 256) w1s[i] = je1_w[i];
  for (int i = tid; i < 64; i += 256) { b1s[i] = je1_b[i]; b2s[i] = je2_b[i]; }
  for (int i = tid; i < 4096; i += 256) w2s[i] = je2_w[i];
  __syncthreads();
  int t = tid;
  if (t >= 224) return;
  float xf[3];
  #pragma unroll
  for (int c = 0; c < 3; ++c) {
    int ch = c * 224 + j;
    float g = bn0[ch], bb = bn0[672 + ch], m = bn0[2 * 672 + ch], v = bn0[3 * 672 + ch];
    float inv = g * rsqrtf(v + EPS);
    float xv = x[((size_t)(b * 3 + c) * 224 + j) * 224 + t];
    xf[c] = (xv - m) * inv + bb;
  }
  float u[64];
  #pragma unroll
  for (int c = 0; c < 64; ++c) {
    float a = w1s[c * 3 + 0] * xf[0] + w1s[c * 3 + 1] * xf[1] + w1s[c * 3 + 2] * xf[2] + b1s[c];
    u[c] = fmaxf(a, 0.f);
  }
  size_t base = ((size_t)(b * 224 + t) * 224 + j) * 128;
  for (int o = 0; o < 64; ++o) {
    float acc = b2s[o];
    #pragma unroll
    for (int c = 0; c < 64; ++c) acc += w2s[o * 64 + c] * u[c];
    H0[base + o] = f2b(fmaxf(acc, 0.f));
  }
  for (int o = 0; o < 64; ++o) H0[base + 64 + o] = f2b(spa1[o * 224 + j]);
}

// ---------------------------------------------------------------------------
// K2: MFMA conv1x1, LDS-staged A via global_load_lds DMA, double buffer,
// XOR-swizzled 16B chunks: chunk(row,kp) at slot row*8 + (kp ^ (row&7)).
// Block 128(M)x128(N), 4 waves 2x2, wave tile 64x64 (4x4 MFMA grid), BK=64.
// Weights (bf16 hi/lo) direct from global (L2-hot).
// Optional transposed output out_t[(bt*Cout + c)*224 + j].
// ---------------------------------------------------------------------------
template <int CIN, int COUT, int DUAL, int WRITE_T>
__global__ __launch_bounds__(256, DUAL ? 2 : 3) void k_conv_mfma(
    const bf16* __restrict__ in1,
    const bf16* __restrict__ w1h, const bf16* __restrict__ w1l,
    const bf16* __restrict__ in2,
    const bf16* __restrict__ w2h, const bf16* __restrict__ w2l,
    const float* __restrict__ bias, const float* __restrict__ bn,
    int do_relu, bf16* __restrict__ out, bf16* __restrict__ out_t) {
  constexpr int BK = 64;
  constexpr int NST = CIN / BK;                 // K-steps
  constexpr int TSZ = 128 * 64;                 // 8192 elems = 16KB per matrix
  __shared__ bf16 smem[2 * (DUAL + 1) * TSZ];
  const int tid = threadIdx.x;
  const int w = tid >> 6, lane = tid & 63;
  const int l15 = lane & 15, q = lane >> 4;
  const int mh = w >> 1, nh = w & 1;
  const int m0 = blockIdx.x * 128;
  const int n0 = blockIdx.y * 128 + nh * 64;

  f32x4 acc[4][4] = {};  // [i][ns]
  // DMA lane decode: slot = (w*4+sh)*64 + lane; row = slot>>3; within a call
  // row&7 == lane>>3, and swizzled kp = (lane&7) ^ (lane>>3)  (lane-constant).
  const int kpl = (lane & 7) ^ (lane >> 3);

  auto issue = [&](int buf, int k0) {
    bf16* b1 = smem + buf * (DUAL + 1) * TSZ;
    #pragma unroll
    for (int sh = 0; sh < 4; ++sh) {
      const int slotbase = (w * 4 + sh) * 64;
      const int row = (slotbase >> 3) + (lane >> 3);
      const bf16* g1 = in1 + (size_t)(m0 + row) * CIN + k0 + kpl * 8;
      gl_lds16(g1, b1 + slotbase * 8);
      if (DUAL) {
        const bf16* g2 = in2 + (size_t)(m0 + row) * CIN + k0 + kpl * 8;
        gl_lds16(g2, b1 + TSZ + slotbase * 8);
      }
    }
  };

  issue(0, 0);
  for (int s = 0; s < NST; ++s) {
    __syncthreads();  // drains this step's DMA (vmcnt0) + release prev buffer
    if (s + 1 < NST) issue((s + 1) & 1, (s + 1) * BK);
    const bf16* base = smem + (s & 1) * (DUAL + 1) * TSZ;
    #pragma unroll
    for (int sub = 0; sub < 2; ++sub) {
      const int kg = s * BK + sub * 32 + q * 8;  // global k offset for weights
      const int kp = sub * 4 + q;                // k-chunk index in tile
      v8s a1[4], a2[4];
      #pragma unroll
      for (int i = 0; i < 4; ++i) {
        const int row = mh * 64 + i * 16 + l15;  // row&7 == l15&7
        const int slot = row * 8 + (kp ^ (l15 & 7));
        a1[i] = *(const v8s*)(base + slot * 8);
        if (DUAL) a2[i] = *(const v8s*)(base + TSZ + slot * 8);
      }
      #pragma unroll
      for (int ns = 0; ns < 4; ++ns) {
        const size_t wrow = (size_t)(n0 + ns * 16 + l15) * CIN + kg;
        v8s bh = *(const v8s*)(w1h + wrow);
        v8s bl = *(const v8s*)(w1l + wrow);
        #pragma unroll
        for (int i = 0; i < 4; ++i) {
          acc[i][ns] = MFMA16(a1[i], bl, acc[i][ns]);
          acc[i][ns] = MFMA16(a1[i], bh, acc[i][ns]);
        }
        if (DUAL) {
          v8s ch = *(const v8s*)(w2h + wrow);
          v8s cl = *(const v8s*)(w2l + wrow);
          #pragma unroll
          for (int i = 0; i < 4; ++i) {
            acc[i][ns] = MFMA16(a2[i], cl, acc[i][ns]);
            acc[i][ns] = MFMA16(a2[i], ch, acc[i][ns]);
          }
        }
      }
    }
  }
  #pragma unroll
  for (int ns = 0; ns < 4; ++ns) {
    const int oc = n0 + ns * 16 + l15;
    float sc = 1.f, sh = bias[oc];
    if (bn != nullptr) {
      float g = bn[oc], bb = bn[COUT + oc], m = bn[2 * COUT + oc], v = bn[3 * COUT + oc];
      sc = g * rsqrtf(v + EPS);
      sh = (sh - m) * sc + bb;
    }
    #pragma unroll
    for (int i = 0; i < 4; ++i) {
      const int mbase = m0 + mh * 64 + i * 16 + q * 4;
      float vals[4];
      #pragma unroll
      for (int r = 0; r < 4; ++r) {
        float val = acc[i][ns][r] * sc + sh;
        if (do_relu) val = fmaxf(val, 0.f);
        vals[r] = val;
        out[(size_t)(mbase + r) * COUT + oc] = f2b(val);
      }
      if (WRITE_T) {
        const int bt = mbase / 224;  // 4-row store group stays in one bt (224%4==0)
        const int j = mbase - bt * 224;
        unsigned short s0 = __bfloat16_as_ushort(f2b(vals[0]));
        unsigned short s1 = __bfloat16_as_ushort(f2b(vals[1]));
        unsigned short s2 = __bfloat16_as_ushort(f2b(vals[2]));
        unsigned short s3 = __bfloat16_as_ushort(f2b(vals[3]));
        uint2 pk;
        pk.x = (unsigned int)s0 | ((unsigned int)s1 << 16);
        pk.y = (unsigned int)s2 | ((unsigned int)s3 << 16);
        *(uint2*)((unsigned short*)out_t + ((size_t)bt * COUT + oc) * 224 + j) = pk;
      }
    }
  }
}

// ---------------------------------------------------------------------------
// K2b: per-chunk transpose of H0c [bt*224+j][128] -> Ht [(bt*128)+c][224]
// ---------------------------------------------------------------------------
__global__ __launch_bounds__(256) void k_transpose128(
    const bf16* __restrict__ src, bf16* __restrict__ dst) {
  const int j0 = blockIdx.x * 32, c0 = blockIdx.y * 32, bt = blockIdx.z;
  __shared__ unsigned short ts[32][33];
  const int tid = threadIdx.x;
  {
    int r = tid >> 3, cg = (tid & 7) * 4;
    const unsigned short* sp =
        (const unsigned short*)src + ((size_t)(bt * 224) + j0 + r) * 128 + c0 + cg;
    uint2 u = *(const uint2*)sp;
    ts[r][cg + 0] = (unsigned short)(u.x & 0xffffu);
    ts[r][cg + 1] = (unsigned short)(u.x >> 16);
    ts[r][cg + 2] = (unsigned short)(u.y & 0xffffu);
    ts[r][cg + 3] = (unsigned short)(u.y >> 16);
  }
  __syncthreads();
  {
    int c = tid >> 3, jg = (tid & 7) * 4;
    uint2 o;
    o.x = (unsigned int)ts[jg + 0][c] | ((unsigned int)ts[jg + 1][c] << 16);
    o.y = (unsigned int)ts[jg + 2][c] | ((unsigned int)ts[jg + 3][c] << 16);
    *(uint2*)((unsigned short*)dst + ((size_t)(bt * 128) + c0 + c) * 224 + j0 + jg) = o;
  }
}

// ---------------------------------------------------------------------------
// K3: MFMA scores + softmax. A[bt*224+j][128], H[bt*224+k][128] ->
// G[bt][j][k] = softmax_k(A_j . H_k). Wave = 16 j-rows x all 224 k.
// ---------------------------------------------------------------------------
__global__ __launch_bounds__(256, 3) void k_scores_mfma(
    const bf16* __restrict__ A, const bf16* __restrict__ H, bf16* __restrict__ G) {
  const int bt = blockIdx.y;
  const int w = threadIdx.x >> 6, lane = threadIdx.x & 63;
  const int mt = blockIdx.x * 4 + w;
  if (mt >= 14) return;
  const int l15 = lane & 15, q = lane >> 4;
  const int j0 = mt * 16;
  const bf16* Ab = A + (size_t)bt * 224 * 128;
  const bf16* Hb = H + (size_t)bt * 224 * 128;
  v8s a[4];
  #pragma unroll
  for (int ks = 0; ks < 4; ++ks)
    a[ks] = *(const v8s*)(Ab + (size_t)(j0 + l15) * 128 + ks * 32 + q * 8);
  f32x4 s[14];
  #pragma unroll
  for (int nt = 0; nt < 14; ++nt) {
    f32x4 acc = {0.f, 0.f, 0.f, 0.f};
    #pragma unroll
    for (int ks = 0; ks < 4; ++ks) {
      v8s b = *(const v8s*)(Hb + (size_t)(nt * 16 + l15) * 128 + ks * 32 + q * 8);
      acc = MFMA16(a[ks], b, acc);
    }
    s[nt] = acc;
  }
  bf16* Gb = G + ((size_t)bt * 224 + j0) * 224;
  #pragma unroll
  for (int r = 0; r < 4; ++r) {
    float mx = -1e30f;
    #pragma unroll
    for (int nt = 0; nt < 14; ++nt) mx = fmaxf(mx, s[nt][r]);
    mx = fmaxf(mx, __shfl_xor(mx, 1));
    mx = fmaxf(mx, __shfl_xor(mx, 2));
    mx = fmaxf(mx, __shfl_xor(mx, 4));
    mx = fmaxf(mx, __shfl_xor(mx, 8));
    float sum = 0.f;
    #pragma unroll
    for (int nt = 0; nt < 14; ++nt) {
      float e = __expf(s[nt][r] - mx);
      s[nt][r] = e;
      sum += e;
    }
    sum += __shfl_xor(sum, 1);
    sum += __shfl_xor(sum, 2);
    sum += __shfl_xor(sum, 4);
    sum += __shfl_xor(sum, 8);
    const float inv = 1.f / sum;
    const int jr = q * 4 + r;
    #pragma unroll
    for (int nt = 0; nt < 14; ++nt)
      Gb[(size_t)jr * 224 + nt * 16 + l15] = f2b(s[nt][r] * inv);
  }
}

// ---------------------------------------------------------------------------
// K4: MFMA apply: Y[bt*224+j][c] = sum_k G[bt][j][k]*Ht[bt][c][k]
// Grid (7, bt). Block = 4 waves sharing the same 32 j-rows, C split 4 ways.
// ---------------------------------------------------------------------------
template <int C>
__global__ __launch_bounds__(256, 3) void k_apply_mfma(
    const bf16* __restrict__ G, const bf16* __restrict__ Ht,
    bf16* __restrict__ Y) {
  const int bt = blockIdx.y;
  const int w = threadIdx.x >> 6;
  const int lane = threadIdx.x & 63;
  const int l15 = lane & 15, q = lane >> 4;
  const int j0 = blockIdx.x * 32;
  const bf16* Gb = G + (size_t)bt * 224 * 224;
  const bf16* Hb = Ht + (size_t)bt * C * 224;
  bf16* Yb = Y + (size_t)bt * 224 * C;
  v8s a[2][7];
  #pragma unroll
  for (int h = 0; h < 2; ++h)
    #pragma unroll
    for (int ks = 0; ks < 7; ++ks)
      a[h][ks] = *(const v8s*)(Gb + (size_t)(j0 + h * 16 + l15) * 224 + ks * 32 + q * 8);
  constexpr int NPW = C / 64;  // nt per wave
  #pragma unroll
  for (int u = 0; u < NPW; ++u) {
    const int nt = w * NPW + u;
    f32x4 acc0 = {0.f, 0.f, 0.f, 0.f};
    f32x4 acc1 = {0.f, 0.f, 0.f, 0.f};
    #pragma unroll
    for (int ks = 0; ks < 7; ++ks) {
      v8s b = *(const v8s*)(Hb + (size_t)(nt * 16 + l15) * 224 + ks * 32 + q * 8);
      acc0 = MFMA16(a[0][ks], b, acc0);
      acc1 = MFMA16(a[1][ks], b, acc1);
    }
    const int c = nt * 16 + l15;
    #pragma unroll
    for (int r = 0; r < 4; ++r) {
      Yb[(size_t)(j0 + q * 4 + r) * C + c] = f2b(acc0[r]);
      Yb[(size_t)(j0 + 16 + q * 4 + r) * C + c] = f2b(acc1[r]);
    }
  }
}

// ---------------------------------------------------------------------------
// K5: partial max over j (32 rows per block) -> atomicMax into Hred (>=0)
// ---------------------------------------------------------------------------
__global__ __launch_bounds__(256) void k_reduce(
    const bf16* __restrict__ H3, float* __restrict__ Hred, int row0) {
  int t = blockIdx.x;
  int jb = blockIdx.y;
  int o = threadIdx.x;
  const unsigned short* p =
      (const unsigned short*)(H3 + ((size_t)t * 224 + jb * 32) * 256 + o);
  float mx = 0.f;
  #pragma unroll 8
  for (int j = 0; j < 32; ++j) mx = fmaxf(mx, bfu(p[(size_t)j * 256]));
  atomicMax((unsigned int*)&Hred[(size_t)(row0 + t) * 256 + o], __float_as_uint(mx));
}

// ---------------------------------------------------------------------------
// K6a: adaptive max pool 224 -> 20 over t, adding tem1[c,t]. Grid (4,20).
// ---------------------------------------------------------------------------
__global__ __launch_bounds__(256) void k_head_a(
    const float* __restrict__ Hred, const float* __restrict__ tem1,
    float* __restrict__ Hm) {
  int b = blockIdx.x, i = blockIdx.y, c = threadIdx.x;
  int s = (i * 224) / 20, e = ((i + 1) * 224 + 19) / 20;
  float mx = -1e30f;
  for (int t = s; t < e; ++t)
    mx = fmaxf(mx, Hred[((size_t)b * 224 + t) * 256 + c] + tem1[c * 224 + t]);
  Hm[((size_t)b * 20 + i) * 256 + c] = mx;
}

// ---------------------------------------------------------------------------
// K6b: loc1 width-3 conv + bn + relu. Grid (4,20), block 256 (o).
// ---------------------------------------------------------------------------
__global__ __launch_bounds__(256) void k_head_b(
    const float* __restrict__ Hm, const float* __restrict__ loc1_w,
    const float* __restrict__ loc1_b, const float* __restrict__ loc1_bn,
    float* __restrict__ Z1) {
  int b = blockIdx.x, r = blockIdx.y;
  __shared__ float hs[3 * 256];
  int tid = threadIdx.x;
  for (int idx = tid; idx < 768; idx += 256) {
    int dx = idx >> 8, c = idx & 255;
    int u = r + dx - 1;
    hs[idx] = (u >= 0 && u < 20) ? Hm[((size_t)b * 20 + u) * 256 + c] : 0.f;
  }
  __syncthreads();
  int o = tid;
  float acc = loc1_b[o];
  const float* wp = loc1_w + (size_t)o * 768;
  #pragma unroll 4
  for (int c = 0; c < 256; ++c) {
    acc += wp[c * 3 + 0] * hs[c] + wp[c * 3 + 1] * hs[256 + c] + wp[c * 3 + 2] * hs[512 + c];
  }
  float g = loc1_bn[o], bb = loc1_bn[256 + o], m = loc1_bn[512 + o], v = loc1_bn[768 + o];
  float sc = g * rsqrtf(v + EPS);
  Z1[((size_t)b * 20 + r) * 256 + o] = fmaxf((acc - m) * sc + bb, 0.f);
}

// ---------------------------------------------------------------------------
// K6c: loc2 + bn + relu + max over 20 positions. Grid 4, block 512 (o2).
// ---------------------------------------------------------------------------
__global__ __launch_bounds__(512) void k_head_c(
    const float* __restrict__ Z1, const float* __restrict__ loc2_w,
    const float* __restrict__ loc2_b, const float* __restrict__ loc2_bn,
    float* __restrict__ out) {
  int b = blockIdx.x;
  int tid = threadIdx.x;
  __shared__ float zs[20 * 256];
  for (int idx = tid; idx < 5120; idx += 512) zs[idx] = Z1[(size_t)b * 5120 + idx];
  __syncthreads();
  int o2 = tid;
  float acc[20];
  float bi = loc2_b[o2];
  #pragma unroll
  for (int r = 0; r < 20; ++r) acc[r] = bi;
  const float* wp = loc2_w + (size_t)o2 * 256;
  for (int c = 0; c < 256; ++c) {
    float wv = wp[c];
    #pragma unroll
    for (int r = 0; r < 20; ++r) acc[r] += wv * zs[r * 256 + c];
  }
  float g = loc2_bn[o2], bb = loc2_bn[512 + o2], m = loc2_bn[1024 + o2], v = loc2_bn[1536 + o2];
  float sc = g * rsqrtf(v + EPS);
  float best = -1e30f;
  #pragma unroll
  for (int r = 0; r < 20; ++r) best = fmaxf(best, fmaxf((acc[r] - m) * sc + bb, 0.f));
  out[(size_t)b * 512 + o2] = best;
}

// ---------------------------------------------------------------------------
extern "C" void kernel_launch(void* const* d_in, const int* in_sizes, int n_in,
                              void* d_out, int out_size, void* d_ws, size_t ws_size,
                              hipStream_t stream) {
  const float* x       = (const float*)d_in[0];
  const float* je1_w   = (const float*)d_in[1];
  const float* je1_b   = (const float*)d_in[2];
  const float* je2_w   = (const float*)d_in[3];
  const float* je2_b   = (const float*)d_in[4];
  const float* se1_w   = (const float*)d_in[5];
  const float* se1_b   = (const float*)d_in[6];
  const float* se2_w   = (const float*)d_in[7];
  const float* se2_b   = (const float*)d_in[8];
  const float* te1_w   = (const float*)d_in[9];
  const float* te1_b   = (const float*)d_in[10];
  const float* te2_w   = (const float*)d_in[11];
  const float* te2_b   = (const float*)d_in[12];
  const float* g1_w    = (const float*)d_in[13];
  const float* g1_b    = (const float*)d_in[14];
  const float* g2_w    = (const float*)d_in[15];
  const float* gcn1_w  = (const float*)d_in[17];
  const float* gcn1_w1 = (const float*)d_in[18];
  const float* gcn1_b  = (const float*)d_in[19];
  const float* gcn2_w  = (const float*)d_in[20];
  const float* gcn2_w1 = (const float*)d_in[21];
  const float* gcn2_b  = (const float*)d_in[22];
  const float* gcn3_w  = (const float*)d_in[23];
  const float* gcn3_w1 = (const float*)d_in[24];
  const float* gcn3_b  = (const float*)d_in[25];
  const float* loc1_w  = (const float*)d_in[26];
  const float* loc1_b  = (const float*)d_in[27];
  const float* loc2_w  = (const float*)d_in[28];
  const float* loc2_b  = (const float*)d_in[29];
  const float* bn0     = (const float*)d_in[30];
  const float* gcn1_bn = (const float*)d_in[31];
  const float* gcn2_bn = (const float*)d_in[32];
  const float* gcn3_bn = (const float*)d_in[33];
  const float* loc1_bn = (const float*)d_in[34];
  const float* loc2_bn = (const float*)d_in[35];
  float* out = (float*)d_out;
  (void)in_sizes; (void)n_in; (void)out_size; (void)ws_size;

  char* ws = (char*)d_ws;
  size_t off = 0;
  auto take = [&](size_t bytes) -> char* {
    char* p = ws + off;
    off += (bytes + 255) & ~(size_t)255;
    return p;
  };
  const size_t M  = 200704;  // 4*224*224 total positions
  const size_t Mc = 50176;   // 224*224 per batch chunk (S=1: L3-friendly)
  float* tem1 = (float*)take(256 * 224 * 4);
  float* spa1 = (float*)take(64 * 224 * 4);
  bf16* WmH   = (bf16*)take(128 * 128 * 2);
  bf16* WmL   = (bf16*)take(128 * 128 * 2);
  float* dvec = (float*)take(128 * 4);
  bf16* wb    = (bf16*)take(458752 * 2);  // gcn weights hi/lo packed
  float* Hm   = (float*)take(4 * 20 * 256 * 4);
  float* Z1   = (float*)take(4 * 20 * 256 * 4);
  float* Hred = (float*)take(896 * 256 * 4);
  bf16* H0 = (bf16*)take(M * 128 * 2);    // full H0 [M,128]
  bf16* YZ = (bf16*)take(Mc * 256 * 2);   // Y half / Z half; Y3 spans both
  bf16* Wb = (bf16*)take(Mc * 256 * 2);   // H2 row-major
  bf16* HtV = (bf16*)take(Mc * 256 * 2);  // Ht (H0t/H1t/H2t) then H3 (conv3 out)
  bf16* Gm = (bf16*)take(Mc * 224 * 2);   // softmax probs per chunk
  bf16* Yr = YZ;
  bf16* Zr = YZ + Mc * 128;

  bf16* g1w_h  = wb;           bf16* g1w_l  = wb + 16384;
  bf16* g1w1_h = wb + 32768;   bf16* g1w1_l = wb + 49152;
  bf16* g2w_h  = wb + 65536;   bf16* g2w_l  = wb + 98304;
  bf16* g2w1_h = wb + 131072;  bf16* g2w1_l = wb + 163840;
  bf16* g3w_h  = wb + 196608;  bf16* g3w_l  = wb + 262144;
  bf16* g3w1_h = wb + 327680;  bf16* g3w1_l = wb + 393216;

  hipMemsetAsync(Hred, 0, 896 * 256 * 4, stream);
  k_small<<<280, 256, 0, stream>>>(te1_w, te1_b, te2_w, te2_b,
                                   se1_w, se1_b, se2_w, se2_b, tem1, spa1);
  k_wm<<<64, 256, 0, stream>>>(g1_w, g2_w, g1_b, WmH, WmL, dvec);
  k_wcvt<<<896, 256, 0, stream>>>(gcn1_w, gcn1_w1, gcn2_w, gcn2_w1, gcn3_w, gcn3_w1, wb);
  k_h0<<<896, 256, 0, stream>>>(x, bn0, je1_w, je1_b, je2_w, je2_b, spa1, H0);

  for (int b = 0; b < 4; ++b) {
    const bf16* H0c = H0 + (size_t)b * Mc * 128;
    // A = H0c @ Wm^T + dvec  (fused q/k)
    k_conv_mfma<128, 128, 0, 0><<<dim3(392, 1), 256, 0, stream>>>(
        H0c, WmH, WmL, nullptr, nullptr, nullptr, dvec, nullptr, 0, Yr, nullptr);
    // H0t for apply1
    k_transpose128<<<dim3(7, 4, 224), 256, 0, stream>>>(H0c, HtV);
    // scores + softmax
    k_scores_mfma<<<dim3(4, 224), 256, 0, stream>>>(Yr, H0c, Gm);
    // gcn1
    k_apply_mfma<128><<<dim3(7, 224), 256, 0, stream>>>(Gm, HtV, Yr);
    k_conv_mfma<128, 128, 1, 1><<<dim3(392, 1), 256, 0, stream>>>(
        Yr, g1w_h, g1w_l, H0c, g1w1_h, g1w1_l, gcn1_b, gcn1_bn, 1, Zr, HtV);
    // gcn2
    k_apply_mfma<128><<<dim3(7, 224), 256, 0, stream>>>(Gm, HtV, Yr);
    k_conv_mfma<128, 256, 1, 1><<<dim3(392, 2), 256, 0, stream>>>(
        Yr, g2w_h, g2w_l, Zr, g2w1_h, g2w1_l, gcn2_b, gcn2_bn, 1, Wb, HtV);
    // gcn3
    k_apply_mfma<256><<<dim3(7, 224), 256, 0, stream>>>(Gm, HtV, YZ);
    k_conv_mfma<256, 256, 1, 0><<<dim3(392, 2), 256, 0, stream>>>(
        YZ, g3w_h, g3w_l, Wb, g3w1_h, g3w1_l, gcn3_b, gcn3_bn, 1, HtV, nullptr);
    // partial max over j into Hred (atomicMax, values >= 0)
    k_reduce<<<dim3(224, 7), 256, 0, stream>>>(HtV, Hred, b * 224);
  }
  k_head_a<<<dim3(4, 20), 256, 0, stream>>>(Hred, tem1, Hm);
  k_head_b<<<dim3(4, 20), 256, 0, stream>>>(Hm, loc1_w, loc1_b, loc1_bn, Z1);
  k_head_c<<<4, 512, 0, stream>>>(Z1, loc2_w, loc2_b, loc2_bn, out);
}